// Round 10
// baseline (164.061 us; speedup 1.0000x reference)
//
#include <hip/hip_runtime.h>
#include <math.h>

#define NN 4096        // nodes
#define DIM 256        // hidden
#define NHEAD 8
#define HDIM 32
#define DFF 512
#define CAP 128        // max nonzeros per row (mean ~41, max ~75 at p=.01)
#define EPS_BN 1e-5f
#define QSCALE 0.0625f // D^-0.5
#define MB (1u << 20)

typedef __attribute__((ext_vector_type(8))) short short8;
typedef __attribute__((ext_vector_type(4))) float f32x4;

__device__ inline ushort f2bf(float x) {   // RNE float->bf16
    unsigned u = __builtin_bit_cast(unsigned, x);
    unsigned r = u + 0x7FFF + ((u >> 16) & 1);
    return (ushort)(r >> 16);
}
__device__ inline float bf2f(ushort u) {
    return __builtin_bit_cast(float, (unsigned)u << 16);
}
__device__ inline float bflo(unsigned u) { return __builtin_bit_cast(float, u << 16); }
__device__ inline float bfhi(unsigned u) { return __builtin_bit_cast(float, u & 0xFFFF0000u); }

// ---------------- convert weights fp32 -> bf16 + zero counters -------------
// 256 blocks: Wq(32) Wk(32) Wv(32) Wo-permuted(32) W1(64) W2(64).
__global__ __launch_bounds__(256) void convert_w(
    const float* __restrict__ Wq, const float* __restrict__ Wk,
    const float* __restrict__ Wv, const float* __restrict__ Wo,
    const float* __restrict__ W1, const float* __restrict__ W2,
    ushort* __restrict__ wqkv, ushort* __restrict__ wo_b,
    ushort* __restrict__ w1_b, ushort* __restrict__ w2_b,
    int* __restrict__ cnts)
{
    int b = blockIdx.x, tid = threadIdx.x;
    if (b == 0 && tid < 8) cnts[tid] = 0;
    if (b >= 96 && b < 128) {
        // Wo permuted convert: dest[row][h*32+d] = src[row][d*8+h]
        int off = b - 96;
        int row = off * 8 + (tid >> 5), t = tid & 31;
        int hh = t >> 2, dd0 = (t & 3) * 8;
        const float* src = Wo + (size_t)row * 256 + hh;
        ushort tmp[8];
        #pragma unroll
        for (int i = 0; i < 8; ++i) tmp[i] = f2bf(src[(size_t)(dd0 + i) * 8]);
        uint4 u;
        u.x = (unsigned)tmp[0] | ((unsigned)tmp[1] << 16);
        u.y = (unsigned)tmp[2] | ((unsigned)tmp[3] << 16);
        u.z = (unsigned)tmp[4] | ((unsigned)tmp[5] << 16);
        u.w = (unsigned)tmp[6] | ((unsigned)tmp[7] << 16);
        *(uint4*)(wo_b + (size_t)row * 256 + hh * 32 + dd0) = u;
        return;
    }
    const float* s; ushort* d; int off;
    if      (b < 32)  { s = Wq; d = wqkv;          off = b; }
    else if (b < 64)  { s = Wk; d = wqkv + 65536;  off = b - 32; }
    else if (b < 96)  { s = Wv; d = wqkv + 131072; off = b - 64; }
    else if (b < 192) { s = W1; d = w1_b;          off = b - 128; }
    else              { s = W2; d = w2_b;          off = b - 192; }
    size_t base = (size_t)off * 2048 + (size_t)tid * 8;
    float4 f0 = *(const float4*)(s + base);
    float4 f1 = *(const float4*)(s + base + 4);
    uint4 u;
    u.x = (unsigned)f2bf(f0.x) | ((unsigned)f2bf(f0.y) << 16);
    u.y = (unsigned)f2bf(f0.z) | ((unsigned)f2bf(f0.w) << 16);
    u.z = (unsigned)f2bf(f1.x) | ((unsigned)f2bf(f1.y) << 16);
    u.w = (unsigned)f2bf(f1.z) | ((unsigned)f2bf(f1.w) << 16);
    *(uint4*)(d + base) = u;
}

// ---------------- fused: QKV gemm (blocks 0..767, fp32 h on-load convert) --
//                  + A nz-scan (768..4863); last v-block reduces vsumh.
#define LDP 88
#define TSTRIDE 74
__global__ __launch_bounds__(256) void qkv_ascan(
    const float* __restrict__ hF, const ushort* __restrict__ B,
    ushort* __restrict__ qh, ushort* __restrict__ kvh,
    float* __restrict__ vpart, float* __restrict__ vsumh,
    const float* __restrict__ Araw, unsigned* __restrict__ packed,
    int* __restrict__ cnt, int* __restrict__ cntV)
{
    __shared__ ushort As[64][LDP];
    __shared__ ushort Bs[64][LDP];
    __shared__ float sRedS[8][64];
    __shared__ int lastF;
    int b = blockIdx.x, tid = threadIdx.x;

    if (b >= 768) {
        // ---- A-scan branch ----
        int* scan = (int*)&As[0][0];
        int n = b - 768;
        const float* row = Araw + (size_t)n * NN;
        float4 vals[4];
        int c = 0;
        #pragma unroll
        for (int i = 0; i < 4; ++i) {
            vals[i] = *(const float4*)(row + i * 1024 + tid * 4);
            c += (vals[i].x != 0.f) + (vals[i].y != 0.f)
               + (vals[i].z != 0.f) + (vals[i].w != 0.f);
        }
        scan[tid] = c;
        __syncthreads();
        for (int off = 1; off < 256; off <<= 1) {
            int t = (tid >= off) ? scan[tid - off] : 0;
            __syncthreads();
            scan[tid] += t;
            __syncthreads();
        }
        int pos = scan[tid] - c;       // exclusive prefix
        int total = scan[255];
        #pragma unroll
        for (int i = 0; i < 4; ++i) {
            int cb = i * 1024 + tid * 4;
            float4 v = vals[i];
            if (v.x != 0.f && pos < CAP) { packed[n*CAP+pos] = ((unsigned)f2bf(v.x) << 16) | (unsigned)cb;       ++pos; }
            if (v.y != 0.f && pos < CAP) { packed[n*CAP+pos] = ((unsigned)f2bf(v.y) << 16) | (unsigned)(cb + 1); ++pos; }
            if (v.z != 0.f && pos < CAP) { packed[n*CAP+pos] = ((unsigned)f2bf(v.z) << 16) | (unsigned)(cb + 2); ++pos; }
            if (v.w != 0.f && pos < CAP) { packed[n*CAP+pos] = ((unsigned)f2bf(v.w) << 16) | (unsigned)(cb + 3); ++pos; }
        }
        if (tid == 0) cnt[n] = min(total, CAP);
        return;
    }

    // ---- QKV GEMM branch (A = fp32 h, converted on load) ----
    int lane = tid & 63, w = tid >> 6;
    int wm = (w >> 1) * 32, wn = (w & 1) * 32;
    int xcd = b & 7, pos = b >> 3;
    int by = xcd * 8 + pos / 12;
    int bx = pos % 12;
    int m0 = by * 64, n0 = bx * 64;
    int l15 = lane & 15, lk = lane >> 4;
    int srow = tid >> 3;
    int scol = (tid & 7) * 8;

    f32x4 acc[2][2] = {};
    for (int k0 = 0; k0 < DIM; k0 += 64) {
        const ushort* Bg = B + (size_t)(n0 + srow) * DIM + scol + k0;
        uint4 gb0 = *(const uint4*)Bg;
        uint4 gb1 = *(const uint4*)(Bg + (size_t)32 * DIM);
        const float* Af = hF + (size_t)(m0 + srow) * DIM + scol + k0;
        float4 a0 = *(const float4*)Af;
        float4 a1 = *(const float4*)(Af + 4);
        float4 c0 = *(const float4*)(Af + (size_t)32 * DIM);
        float4 c1 = *(const float4*)(Af + (size_t)32 * DIM + 4);
        uint4 ga0, ga1;
        ga0.x = (unsigned)f2bf(a0.x) | ((unsigned)f2bf(a0.y) << 16);
        ga0.y = (unsigned)f2bf(a0.z) | ((unsigned)f2bf(a0.w) << 16);
        ga0.z = (unsigned)f2bf(a1.x) | ((unsigned)f2bf(a1.y) << 16);
        ga0.w = (unsigned)f2bf(a1.z) | ((unsigned)f2bf(a1.w) << 16);
        ga1.x = (unsigned)f2bf(c0.x) | ((unsigned)f2bf(c0.y) << 16);
        ga1.y = (unsigned)f2bf(c0.z) | ((unsigned)f2bf(c0.w) << 16);
        ga1.z = (unsigned)f2bf(c1.x) | ((unsigned)f2bf(c1.y) << 16);
        ga1.w = (unsigned)f2bf(c1.z) | ((unsigned)f2bf(c1.w) << 16);
        __syncthreads();
        *(uint4*)&As[srow][scol]      = ga0;
        *(uint4*)&As[srow + 32][scol] = ga1;
        *(uint4*)&Bs[srow][scol]      = gb0;
        *(uint4*)&Bs[srow + 32][scol] = gb1;
        __syncthreads();
        #pragma unroll
        for (int ks = 0; ks < 2; ++ks) {
            int kc = ks * 32 + lk * 8;
            short8 a0s = *(const short8*)&As[wm      + l15][kc];
            short8 a1s = *(const short8*)&As[wm + 16 + l15][kc];
            short8 b0s = *(const short8*)&Bs[wn      + l15][kc];
            short8 b1s = *(const short8*)&Bs[wn + 16 + l15][kc];
            acc[0][0] = __builtin_amdgcn_mfma_f32_16x16x32_bf16(a0s, b0s, acc[0][0], 0, 0, 0);
            acc[0][1] = __builtin_amdgcn_mfma_f32_16x16x32_bf16(a0s, b1s, acc[0][1], 0, 0, 0);
            acc[1][0] = __builtin_amdgcn_mfma_f32_16x16x32_bf16(a1s, b0s, acc[1][0], 0, 0, 0);
            acc[1][1] = __builtin_amdgcn_mfma_f32_16x16x32_bf16(a1s, b1s, acc[1][1], 0, 0, 0);
        }
    }
    // transpose via LDS (reuse As), coalesced 16B chunk stores
    ushort* sT = &As[0][0];
    int seg = n0 >> 8, ddBase = (n0 & 255) >> 3;
    float sp[2] = {0.f, 0.f};
    __syncthreads();
    #pragma unroll
    for (int mt = 0; mt < 2; ++mt)
        #pragma unroll
        for (int nt = 0; nt < 2; ++nt) {
            int col_l = wn + nt * 16 + l15;
            #pragma unroll
            for (int i = 0; i < 4; ++i) {
                int row_l = wm + mt * 16 + lk * 4 + i;
                float v = acc[mt][nt][i];
                if (seg == 0) v *= QSCALE;
                sT[row_l * TSTRIDE + col_l] = f2bf(v);
                sp[nt] += v;
            }
        }
    __syncthreads();
    for (int c = tid; c < 512; c += 256) {
        int rl = c & 63, hh = c >> 6;
        const ushort* tp = sT + rl * TSTRIDE + hh;
        uint4 pk;
        pk.x = (unsigned)tp[0]  | ((unsigned)tp[8]  << 16);
        pk.y = (unsigned)tp[16] | ((unsigned)tp[24] << 16);
        pk.z = (unsigned)tp[32] | ((unsigned)tp[40] << 16);
        pk.w = (unsigned)tp[48] | ((unsigned)tp[56] << 16);
        int row = m0 + rl;
        if (seg == 0)
            *(uint4*)(qh + ((size_t)hh * NN + row) * HDIM + ddBase) = pk;
        else
            *(uint4*)(kvh + ((size_t)hh * NN + row) * 64 +
                      ((seg == 2) ? 32 : 0) + ddBase) = pk;
    }
    if (seg == 2) {
        int slot = ((wm >> 5) << 2) | lk;
        sRedS[slot][wn + l15]      = sp[0];
        sRedS[slot][wn + 16 + l15] = sp[1];
        __syncthreads();
        if (tid < 64) {
            float ss = 0.f;
            #pragma unroll
            for (int r = 0; r < 8; ++r) ss += sRedS[r][tid];
            vpart[(size_t)by * 256 + (n0 & 255) + tid] = ss;
        }
        // last of the 256 v-blocks reduces vpart -> vsumh
        __threadfence();
        if (tid == 0) lastF = (atomicAdd(cntV, 1) == 255);
        __syncthreads();
        if (lastF) {
            __threadfence();
            int c = tid;
            float s = 0.f;
            #pragma unroll 8
            for (int bb = 0; bb < 64; ++bb) s += vpart[(size_t)bb * 256 + c];
            vsumh[(c & 7) * HDIM + (c >> 3)] = s;
        }
    }
}

// ---------------- bf16 MFMA GEMM (modes 0/1/2/3), XCD-swizzled -------------
// aMode 0: A bf16 [M,K]. aMode 1: A fp32 + on-load BN (scA/shA per col).
// aMode 2: A bf16 head-major [8][NN][32] (B k-permuted to match).
// storeMode 0: Cf fp32 (+resid). 1: Cb bf16 (relu opt).
//   3: Cf fp32, residual recomputed as yres*scR+shR (Cf may alias yres).
// bnstat: per-block col sum/sumsq partials -> bnps/bnpq [nby][256];
//   the LAST block (device atomic) reduces them to scale/shift (g, bsh).
__global__ __launch_bounds__(256) void gemm_bf(
    const void* __restrict__ Aptr, const ushort* __restrict__ B,
    const float* __restrict__ scA, const float* __restrict__ shA,
    const float* __restrict__ resid,
    const float* yres, const float* __restrict__ scR, const float* __restrict__ shR,
    float* Cf, ushort* __restrict__ Cb,
    float* __restrict__ bnps, float* __restrict__ bnpq,
    int* __restrict__ lastCnt, const float* __restrict__ g,
    const float* __restrict__ bsh, float* __restrict__ scaleOut,
    float* __restrict__ shiftOut,
    int M, int Nn, int K, int aMode, int storeMode, int relu, int bnstat)
{
    __shared__ ushort As[64][LDP];
    __shared__ ushort Bs[64][LDP];
    __shared__ float sRedS[8][64];
    __shared__ float sRedQ[8][64];
    __shared__ int lastF;
    int tid = threadIdx.x;
    int lane = tid & 63, w = tid >> 6;
    int wm = (w >> 1) * 32, wn = (w & 1) * 32;
    int nbx = gridDim.x, nbyq = gridDim.y >> 3;
    int orig = blockIdx.y * nbx + blockIdx.x;
    int xcd = orig & 7, pos = orig >> 3;
    int by = xcd * nbyq + pos / nbx;
    int bx = pos % nbx;
    int m0 = by * 64, n0 = bx * 64;
    int l15 = lane & 15, lk = lane >> 4;
    int srow = tid >> 3;
    int scol = (tid & 7) * 8;

    f32x4 acc[2][2] = {};
    for (int k0 = 0; k0 < K; k0 += 64) {
        uint4 ga0, ga1, gb0, gb1;
        const ushort* Bg = B + (size_t)(n0 + srow) * K + scol + k0;
        gb0 = *(const uint4*)Bg;
        gb1 = *(const uint4*)(Bg + (size_t)32 * K);
        if (aMode == 0) {
            const ushort* Ag = (const ushort*)Aptr + (size_t)(m0 + srow) * K + scol + k0;
            ga0 = *(const uint4*)Ag;
            ga1 = *(const uint4*)(Ag + (size_t)32 * K);
        } else if (aMode == 2) {
            int c0 = k0 + scol;
            int hh = c0 >> 5, dd = c0 & 31;
            const ushort* Ag = (const ushort*)Aptr +
                ((size_t)hh * NN + m0 + srow) * HDIM + dd;
            ga0 = *(const uint4*)Ag;
            ga1 = *(const uint4*)(Ag + (size_t)32 * HDIM);
        } else {
            const float* Af = (const float*)Aptr + (size_t)(m0 + srow) * K + scol + k0;
            float4 sc0 = *(const float4*)(scA + k0 + scol);
            float4 sc1 = *(const float4*)(scA + k0 + scol + 4);
            float4 sh0 = *(const float4*)(shA + k0 + scol);
            float4 sh1 = *(const float4*)(shA + k0 + scol + 4);
            float4 a0 = *(const float4*)Af;
            float4 a1 = *(const float4*)(Af + 4);
            float4 b0 = *(const float4*)(Af + (size_t)32 * K);
            float4 b1 = *(const float4*)(Af + (size_t)32 * K + 4);
            ga0.x = (unsigned)f2bf(a0.x*sc0.x+sh0.x) | ((unsigned)f2bf(a0.y*sc0.y+sh0.y) << 16);
            ga0.y = (unsigned)f2bf(a0.z*sc0.z+sh0.z) | ((unsigned)f2bf(a0.w*sc0.w+sh0.w) << 16);
            ga0.z = (unsigned)f2bf(a1.x*sc1.x+sh1.x) | ((unsigned)f2bf(a1.y*sc1.y+sh1.y) << 16);
            ga0.w = (unsigned)f2bf(a1.z*sc1.z+sh1.z) | ((unsigned)f2bf(a1.w*sc1.w+sh1.w) << 16);
            ga1.x = (unsigned)f2bf(b0.x*sc0.x+sh0.x) | ((unsigned)f2bf(b0.y*sc0.y+sh0.y) << 16);
            ga1.y = (unsigned)f2bf(b0.z*sc0.z+sh0.z) | ((unsigned)f2bf(b0.w*sc0.w+sh0.w) << 16);
            ga1.z = (unsigned)f2bf(b1.x*sc1.x+sh1.x) | ((unsigned)f2bf(b1.y*sc1.y+sh1.y) << 16);
            ga1.w = (unsigned)f2bf(b1.z*sc1.z+sh1.z) | ((unsigned)f2bf(b1.w*sc1.w+sh1.w) << 16);
        }
        __syncthreads();
        *(uint4*)&As[srow][scol]      = ga0;
        *(uint4*)&As[srow + 32][scol] = ga1;
        *(uint4*)&Bs[srow][scol]      = gb0;
        *(uint4*)&Bs[srow + 32][scol] = gb1;
        __syncthreads();
        #pragma unroll
        for (int ks = 0; ks < 2; ++ks) {
            int kc = ks * 32 + lk * 8;
            short8 a0 = *(const short8*)&As[wm      + l15][kc];
            short8 a1 = *(const short8*)&As[wm + 16 + l15][kc];
            short8 b0 = *(const short8*)&Bs[wn      + l15][kc];
            short8 b1 = *(const short8*)&Bs[wn + 16 + l15][kc];
            acc[0][0] = __builtin_amdgcn_mfma_f32_16x16x32_bf16(a0, b0, acc[0][0], 0, 0, 0);
            acc[0][1] = __builtin_amdgcn_mfma_f32_16x16x32_bf16(a0, b1, acc[0][1], 0, 0, 0);
            acc[1][0] = __builtin_amdgcn_mfma_f32_16x16x32_bf16(a1, b0, acc[1][0], 0, 0, 0);
            acc[1][1] = __builtin_amdgcn_mfma_f32_16x16x32_bf16(a1, b1, acc[1][1], 0, 0, 0);
        }
    }

    float sp[2] = {0.f, 0.f}, qp[2] = {0.f, 0.f};
    #pragma unroll
    for (int mt = 0; mt < 2; ++mt) {
        #pragma unroll
        for (int nt = 0; nt < 2; ++nt) {
            int col = n0 + wn + nt * 16 + l15;
            #pragma unroll
            for (int i = 0; i < 4; ++i) {
                int row = m0 + wm + mt * 16 + lk * 4 + i;
                float v = acc[mt][nt][i];
                if (storeMode == 0) {
                    if (resid) v += resid[(size_t)row * Nn + col];
                    Cf[(size_t)row * Nn + col] = v;
                } else if (storeMode == 1) {
                    if (relu) v = fmaxf(v, 0.f);
                    Cb[(size_t)row * Nn + col] = f2bf(v);
                } else { // 3
                    v += yres[(size_t)row * Nn + col] * scR[col] + shR[col];
                    Cf[(size_t)row * Nn + col] = v;
                }
                if (bnstat) { sp[nt] += v; qp[nt] += v * v; }
            }
        }
    }
    if (bnstat) {
        int slot = ((wm >> 5) << 2) | lk;
        sRedS[slot][wn + l15]      = sp[0];
        sRedQ[slot][wn + l15]      = qp[0];
        sRedS[slot][wn + 16 + l15] = sp[1];
        sRedQ[slot][wn + 16 + l15] = qp[1];
        __syncthreads();
        if (tid < 64) {
            float ss = 0.f, qq = 0.f;
            #pragma unroll
            for (int r = 0; r < 8; ++r) { ss += sRedS[r][tid]; qq += sRedQ[r][tid]; }
            bnps[(size_t)by * DIM + n0 + tid] = ss;
            bnpq[(size_t)by * DIM + n0 + tid] = qq;
        }
        // last block reduces partials -> scale/shift
        __threadfence();
        if (tid == 0)
            lastF = (atomicAdd(lastCnt, 1) == (int)(gridDim.x * gridDim.y) - 1);
        __syncthreads();
        if (lastF) {
            __threadfence();
            int c = tid;
            float s = 0.f, q = 0.f;
            #pragma unroll 4
            for (int bb = 0; bb < 64; ++bb) {
                s += bnps[(size_t)bb * DIM + c];
                q += bnpq[(size_t)bb * DIM + c];
            }
            float m = s * (1.f / NN);
            float var = q * (1.f / NN) - m * m;
            float rstd = rsqrtf(var + EPS_BN);
            float sc = rstd * g[c];
            scaleOut[c] = sc;
            shiftOut[c] = bsh[c] - m * sc;
        }
    }
}

__global__ __launch_bounds__(256) void bn_apply_fin(
    const float* __restrict__ x, const float* __restrict__ scale,
    const float* __restrict__ shift, float* __restrict__ out)
{
    int tid = threadIdx.x;
    size_t i = (size_t)blockIdx.x * 1024 + (size_t)tid * 4;
    int c = (tid * 4) & 255;
    float4 v = *(const float4*)(x + i);
    float4 sc = *(const float4*)(scale + c);
    float4 sh = *(const float4*)(shift + c);
    float4 r;
    r.x = v.x * sc.x + sh.x;
    r.y = v.y * sc.y + sh.y;
    r.z = v.z * sc.z + sh.z;
    r.w = v.w * sc.w + sh.w;
    *(float4*)(out + i) = r;
}

// ---------------- head-partitioned sparse masked attention -----------------
// Block b: head hH = b&7 (-> XCD b&7), rows rg*8..rg*8+7. Per-XCD working
// set = one head's q+kv (~768 KB) -> L2-resident. No-max-shift softmax.
__global__ __launch_bounds__(256) void attn3(
    const ushort* __restrict__ qh, const ushort* __restrict__ kvh,
    const float* __restrict__ vsumh,
    const unsigned* __restrict__ packed, const int* __restrict__ cnt,
    ushort* __restrict__ outh)
{
    __shared__ float    sQ[8][32];
    __shared__ unsigned sPk[8][CAP];
    __shared__ float    sS[8][CAP];
    __shared__ float    sRd[8];

    int tid = threadIdx.x, b = blockIdx.x;
    int hH = b & 7, rg = b >> 3;
    int r = tid >> 5, l = tid & 31;
    int n = rg * 8 + r;
    int nnz = cnt[n];

    sQ[r][l] = bf2f(qh[((size_t)hH * NN + n) * HDIM + l]);
    for (int j = l; j < nnz; j += 32) sPk[r][j] = packed[n * CAP + j];
    __syncthreads();

    // phase 1: scores + weights + denom (32 lanes split j within the row)
    float4 qreg[8];
    #pragma unroll
    for (int t = 0; t < 8; ++t) qreg[t] = ((const float4*)sQ[r])[t];
    float lsum = 0.0f;
    for (int j = l; j < nnz; j += 32) {
        unsigned pk = sPk[r][j];
        int m = pk & 0xFFFF;
        float a = bfhi(pk);
        const uint4* kp = (const uint4*)(kvh + ((size_t)hH * NN + m) * 64);
        uint4 k0 = kp[0], k1 = kp[1], k2 = kp[2], k3 = kp[3];
        float s =
            bflo(k0.x)*qreg[0].x + bfhi(k0.x)*qreg[0].y +
            bflo(k0.y)*qreg[0].z + bfhi(k0.y)*qreg[0].w +
            bflo(k0.z)*qreg[1].x + bfhi(k0.z)*qreg[1].y +
            bflo(k0.w)*qreg[1].z + bfhi(k0.w)*qreg[1].w +
            bflo(k1.x)*qreg[2].x + bfhi(k1.x)*qreg[2].y +
            bflo(k1.y)*qreg[2].z + bfhi(k1.y)*qreg[2].w +
            bflo(k1.z)*qreg[3].x + bfhi(k1.z)*qreg[3].y +
            bflo(k1.w)*qreg[3].z + bfhi(k1.w)*qreg[3].w +
            bflo(k2.x)*qreg[4].x + bfhi(k2.x)*qreg[4].y +
            bflo(k2.y)*qreg[4].z + bfhi(k2.y)*qreg[4].w +
            bflo(k2.z)*qreg[5].x + bfhi(k2.z)*qreg[5].y +
            bflo(k2.w)*qreg[5].z + bfhi(k2.w)*qreg[5].w +
            bflo(k3.x)*qreg[6].x + bfhi(k3.x)*qreg[6].y +
            bflo(k3.y)*qreg[6].z + bfhi(k3.y)*qreg[6].w +
            bflo(k3.z)*qreg[7].x + bfhi(k3.z)*qreg[7].y +
            bflo(k3.w)*qreg[7].z + bfhi(k3.w)*qreg[7].w;
        s *= a;
        float ww = __expf(s);
        sS[r][j] = ww - 1.0f;
        lsum += ww;
    }
    #pragma unroll
    for (int o = 16; o > 0; o >>= 1) lsum += __shfl_xor(lsum, o, 32);
    if (l == 0) sRd[r] = 1.0f / (lsum + (float)(NN - nnz));
    __syncthreads();

    // phase 2: lane = (jsub = l>>3, dq = l&7); 4-way j split, uint2 gathers
    int jsub = l >> 3, dq = l & 7;
    const ushort* vbase = kvh + (size_t)hH * NN * 64 + 32 + dq * 4;
    float a0 = 0.f, a1 = 0.f, a2 = 0.f, a3 = 0.f;
    for (int j = jsub; j < nnz; j += 4) {
        float ww = sS[r][j];
        int m = sPk[r][j] & 0xFFFF;
        uint2 vv = *(const uint2*)(vbase + (size_t)m * 64);
        a0 += ww * bflo(vv.x); a1 += ww * bfhi(vv.x);
        a2 += ww * bflo(vv.y); a3 += ww * bfhi(vv.y);
    }
    #pragma unroll
    for (int o = 8; o < 32; o <<= 1) {
        a0 += __shfl_xor(a0, o, 32);
        a1 += __shfl_xor(a1, o, 32);
        a2 += __shfl_xor(a2, o, 32);
        a3 += __shfl_xor(a3, o, 32);
    }
    if (jsub == 0) {
        float rd = sRd[r];
        int d0 = dq * 4;
        const float* vs = vsumh + hH * HDIM + d0;
        float r0 = (a0 + vs[0]) * rd;
        float r1 = (a1 + vs[1]) * rd;
        float r2 = (a2 + vs[2]) * rd;
        float r3 = (a3 + vs[3]) * rd;
        uint2 st;
        st.x = (unsigned)f2bf(r0) | ((unsigned)f2bf(r1) << 16);
        st.y = (unsigned)f2bf(r2) | ((unsigned)f2bf(r3) << 16);
        *(uint2*)(outh + ((size_t)hH * NN + n) * HDIM + d0) = st;
    }
}

// ---------------------------------------------------------------------------
extern "C" void kernel_launch(void* const* d_in, const int* in_sizes, int n_in,
                              void* d_out, int out_size, void* d_ws, size_t ws_size,
                              hipStream_t stream)
{
    const float* A  = (const float*)d_in[0];
    const float* h  = (const float*)d_in[1];
    const float* Wq = (const float*)d_in[2];
    const float* Wk = (const float*)d_in[3];
    const float* Wv = (const float*)d_in[4];
    const float* Wo = (const float*)d_in[5];
    const float* g1 = (const float*)d_in[6];
    const float* b1 = (const float*)d_in[7];
    const float* g2 = (const float*)d_in[8];
    const float* b2 = (const float*)d_in[9];
    const float* W1 = (const float*)d_in[10];
    const float* W2 = (const float*)d_in[11];
    float* out = (float*)d_out;
    char* w = (char*)d_ws;

    unsigned* packed = (unsigned*)(w);           // [0,2M)  nz lists
    int*    nzcnt  = (int*)(w + 2 * MB);
    ushort* wqkv   = (ushort*)(w + 5 * MB);      // 384 KB
    ushort* wo_b   = (ushort*)(w + 5 * MB + 384 * 1024);   // k-permuted Wo
    ushort* w1_b   = (ushort*)(w + 5 * MB + 512 * 1024);
    ushort* w2_b   = (ushort*)(w + 5 * MB + 768 * 1024);
    ushort* qh_bf  = (ushort*)(w + 6 * MB);      // 2 MB [8][4096][32]
    ushort* kvh    = (ushort*)(w + 8 * MB);      // 4 MB [8][4096][64] k|v
    ushort* ao_hb  = (ushort*)(w + 12 * MB);     // 2 MB [8][4096][32] head-major
    float*  y      = (float*)(w + 14 * MB);      // 4 MB
    ushort* t_bf   = (ushort*)(w + 18 * MB);     // 4 MB FFN hidden
    float*  vpart  = (float*)(w + 22 * MB);      // 64 KB [64][256]
    float*  bnps1  = (float*)(w + 23 * MB);
    float*  bnpq1  = (float*)(w + 23 * MB + 64 * 1024);
    float*  bnps2  = (float*)(w + 23 * MB + 128 * 1024);
    float*  bnpq2  = (float*)(w + 23 * MB + 192 * 1024);
    float*  scale1 = (float*)(w + 24 * MB);
    float*  shift1 = scale1 + 256;
    float*  scale2 = scale1 + 512;
    float*  shift2 = scale1 + 768;
    float*  vsumh  = scale1 + 1024;
    int*    cnts   = (int*)(w + 25 * MB);        // [vsum, bn1, bn2]

    dim3 blk(256);

    // 1: weight conversions (Wo k-permuted) + counter zeroing
    convert_w<<<256, blk, 0, stream>>>(Wq, Wk, Wv, Wo, W1, W2,
        wqkv, wo_b, w1_b, w2_b, cnts);
    // 2: fused QKV gemm (fp32 h on-load) + A nz-scan; last v-block -> vsumh
    qkv_ascan<<<4864, blk, 0, stream>>>(h, wqkv, qh_bf, kvh, vpart, vsumh,
                                        A, packed, nzcnt, cnts + 0);
    // 3: head-partitioned attention -> head-major ao_hb
    attn3<<<NN, blk, 0, stream>>>(qh_bf, kvh, vsumh, packed, nzcnt, ao_hb);
    // 4: Wo projection + residual(h) -> y; last block -> scale1/shift1
    gemm_bf<<<dim3(4, 64), blk, 0, stream>>>(ao_hb, wo_b,
        nullptr, nullptr, h, nullptr, nullptr, nullptr,
        y, nullptr, bnps1, bnpq1, cnts + 1, g1, b1, scale1, shift1,
        NN, DIM, DIM, 2, 0, 0, 1);
    // 5: FFN1 with BN1 applied on A-load, relu, bf16 out
    gemm_bf<<<dim3(8, 64), blk, 0, stream>>>(y, w1_b,
        scale1, shift1, nullptr, nullptr, nullptr, nullptr,
        nullptr, t_bf, nullptr, nullptr, nullptr, nullptr, nullptr,
        nullptr, nullptr, NN, DFF, DIM, 1, 1, 1, 0);
    // 6: FFN2 + recomputed BN1 residual (in-place y); last block -> scale2/shift2
    gemm_bf<<<dim3(4, 64), blk, 0, stream>>>(t_bf, w2_b,
        nullptr, nullptr, nullptr, y, scale1, shift1,
        y, nullptr, bnps2, bnpq2, cnts + 2, g2, b2, scale2, shift2,
        NN, DIM, DFF, 0, 3, 0, 1);
    // 7: BN2 apply -> d_out
    bn_apply_fin<<<1024, blk, 0, stream>>>(y, scale2, shift2, out);
}

// Round 11
// 103.669 us; speedup vs baseline: 1.5825x; 1.5825x over previous
//
#include <hip/hip_runtime.h>
#include <math.h>

#define NN 4096        // nodes
#define DIM 256        // hidden
#define NHEAD 8
#define HDIM 32
#define DFF 512
#define CAP 128        // max nonzeros per row (mean ~41, max ~75 at p=.01)
#define EPS_BN 1e-5f
#define QSCALE 0.0625f // D^-0.5
#define MB (1u << 20)

typedef __attribute__((ext_vector_type(8))) short short8;
typedef __attribute__((ext_vector_type(4))) float f32x4;

__device__ inline ushort f2bf(float x) {   // RNE float->bf16
    unsigned u = __builtin_bit_cast(unsigned, x);
    unsigned r = u + 0x7FFF + ((u >> 16) & 1);
    return (ushort)(r >> 16);
}
__device__ inline float bf2f(ushort u) {
    return __builtin_bit_cast(float, (unsigned)u << 16);
}
__device__ inline float bflo(unsigned u) { return __builtin_bit_cast(float, u << 16); }
__device__ inline float bfhi(unsigned u) { return __builtin_bit_cast(float, u & 0xFFFF0000u); }

// ---------------- convert: fp32 -> bf16 (h + all weights) ------------------
// Wo (blocks 608..639) stored with k-columns permuted to [h*32+d] order
// so the Wo GEMM can consume head-major attention output directly.
__global__ __launch_bounds__(256) void convert_bf(
    const float* __restrict__ s0, const float* __restrict__ s1,
    const float* __restrict__ s2, const float* __restrict__ s3,
    const float* __restrict__ s4, const float* __restrict__ s5,
    const float* __restrict__ s6,
    ushort* d0, ushort* d1, ushort* d2, ushort* d3,
    ushort* d4, ushort* d5, ushort* d6)
{
    int b = blockIdx.x, tid = threadIdx.x;
    if (b >= 608 && b < 640) {
        // Wo permuted convert: dest[row][h*32+d] = src[row][d*8+h]
        int off = b - 608;
        int row = off * 8 + (tid >> 5), t = tid & 31;
        int hh = t >> 2, dd0 = (t & 3) * 8;
        const float* src = s4 + (size_t)row * 256 + hh;
        ushort tmp[8];
        #pragma unroll
        for (int i = 0; i < 8; ++i) tmp[i] = f2bf(src[(size_t)(dd0 + i) * 8]);
        uint4 u;
        u.x = (unsigned)tmp[0] | ((unsigned)tmp[1] << 16);
        u.y = (unsigned)tmp[2] | ((unsigned)tmp[3] << 16);
        u.z = (unsigned)tmp[4] | ((unsigned)tmp[5] << 16);
        u.w = (unsigned)tmp[6] | ((unsigned)tmp[7] << 16);
        *(uint4*)(d4 + (size_t)row * 256 + hh * 32 + dd0) = u;
        return;
    }
    const float* s; ushort* d; int off;
    if      (b < 512) { s = s0; d = d0; off = b; }
    else if (b < 544) { s = s1; d = d1; off = b - 512; }
    else if (b < 576) { s = s2; d = d2; off = b - 544; }
    else if (b < 608) { s = s3; d = d3; off = b - 576; }
    else if (b < 704) { s = s5; d = d5; off = b - 640; }
    else              { s = s6; d = d6; off = b - 704; }
    size_t base = (size_t)off * 2048 + (size_t)tid * 8;
    float4 f0 = *(const float4*)(s + base);
    float4 f1 = *(const float4*)(s + base + 4);
    uint4 u;
    u.x = (unsigned)f2bf(f0.x) | ((unsigned)f2bf(f0.y) << 16);
    u.y = (unsigned)f2bf(f0.z) | ((unsigned)f2bf(f0.w) << 16);
    u.z = (unsigned)f2bf(f1.x) | ((unsigned)f2bf(f1.y) << 16);
    u.w = (unsigned)f2bf(f1.z) | ((unsigned)f2bf(f1.w) << 16);
    *(uint4*)(d + base) = u;
}

// ---------------- fused: QKV gemm (blocks 0..767) + A nz-scan (768..4863) --
#define LDP 88
#define TSTRIDE 74
__global__ __launch_bounds__(256) void qkv_ascan(
    const ushort* __restrict__ Ah, const ushort* __restrict__ B,
    ushort* __restrict__ qh, ushort* __restrict__ kvh,
    float* __restrict__ vpart,
    const float* __restrict__ Araw, unsigned* __restrict__ packed,
    int* __restrict__ cnt)
{
    __shared__ ushort As[64][LDP];
    __shared__ ushort Bs[64][LDP];
    __shared__ float sRedS[8][64];
    int b = blockIdx.x, tid = threadIdx.x;

    if (b >= 768) {
        // ---- A-scan branch ----
        int* scan = (int*)&As[0][0];
        int n = b - 768;
        const float* row = Araw + (size_t)n * NN;
        float4 vals[4];
        int c = 0;
        #pragma unroll
        for (int i = 0; i < 4; ++i) {
            vals[i] = *(const float4*)(row + i * 1024 + tid * 4);
            c += (vals[i].x != 0.f) + (vals[i].y != 0.f)
               + (vals[i].z != 0.f) + (vals[i].w != 0.f);
        }
        scan[tid] = c;
        __syncthreads();
        for (int off = 1; off < 256; off <<= 1) {
            int t = (tid >= off) ? scan[tid - off] : 0;
            __syncthreads();
            scan[tid] += t;
            __syncthreads();
        }
        int pos = scan[tid] - c;       // exclusive prefix
        int total = scan[255];
        #pragma unroll
        for (int i = 0; i < 4; ++i) {
            int cb = i * 1024 + tid * 4;
            float4 v = vals[i];
            if (v.x != 0.f && pos < CAP) { packed[n*CAP+pos] = ((unsigned)f2bf(v.x) << 16) | (unsigned)cb;       ++pos; }
            if (v.y != 0.f && pos < CAP) { packed[n*CAP+pos] = ((unsigned)f2bf(v.y) << 16) | (unsigned)(cb + 1); ++pos; }
            if (v.z != 0.f && pos < CAP) { packed[n*CAP+pos] = ((unsigned)f2bf(v.z) << 16) | (unsigned)(cb + 2); ++pos; }
            if (v.w != 0.f && pos < CAP) { packed[n*CAP+pos] = ((unsigned)f2bf(v.w) << 16) | (unsigned)(cb + 3); ++pos; }
        }
        if (tid == 0) cnt[n] = min(total, CAP);
        return;
    }

    // ---- QKV GEMM branch ----
    int lane = tid & 63, w = tid >> 6;
    int wm = (w >> 1) * 32, wn = (w & 1) * 32;
    int xcd = b & 7, pos = b >> 3;
    int by = xcd * 8 + pos / 12;
    int bx = pos % 12;
    int m0 = by * 64, n0 = bx * 64;
    int l15 = lane & 15, lk = lane >> 4;
    int srow = tid >> 3;
    int scol = (tid & 7) * 8;

    f32x4 acc[2][2] = {};
    for (int k0 = 0; k0 < DIM; k0 += 64) {
        const ushort* Bg = B + (size_t)(n0 + srow) * DIM + scol + k0;
        uint4 gb0 = *(const uint4*)Bg;
        uint4 gb1 = *(const uint4*)(Bg + (size_t)32 * DIM);
        const ushort* Ag = Ah + (size_t)(m0 + srow) * DIM + scol + k0;
        uint4 ga0 = *(const uint4*)Ag;
        uint4 ga1 = *(const uint4*)(Ag + (size_t)32 * DIM);
        __syncthreads();
        *(uint4*)&As[srow][scol]      = ga0;
        *(uint4*)&As[srow + 32][scol] = ga1;
        *(uint4*)&Bs[srow][scol]      = gb0;
        *(uint4*)&Bs[srow + 32][scol] = gb1;
        __syncthreads();
        #pragma unroll
        for (int ks = 0; ks < 2; ++ks) {
            int kc = ks * 32 + lk * 8;
            short8 a0 = *(const short8*)&As[wm      + l15][kc];
            short8 a1 = *(const short8*)&As[wm + 16 + l15][kc];
            short8 b0 = *(const short8*)&Bs[wn      + l15][kc];
            short8 b1 = *(const short8*)&Bs[wn + 16 + l15][kc];
            acc[0][0] = __builtin_amdgcn_mfma_f32_16x16x32_bf16(a0, b0, acc[0][0], 0, 0, 0);
            acc[0][1] = __builtin_amdgcn_mfma_f32_16x16x32_bf16(a0, b1, acc[0][1], 0, 0, 0);
            acc[1][0] = __builtin_amdgcn_mfma_f32_16x16x32_bf16(a1, b0, acc[1][0], 0, 0, 0);
            acc[1][1] = __builtin_amdgcn_mfma_f32_16x16x32_bf16(a1, b1, acc[1][1], 0, 0, 0);
        }
    }
    // transpose via LDS (reuse As), coalesced 16B chunk stores
    ushort* sT = &As[0][0];
    int seg = n0 >> 8, ddBase = (n0 & 255) >> 3;
    float sp[2] = {0.f, 0.f};
    __syncthreads();
    #pragma unroll
    for (int mt = 0; mt < 2; ++mt)
        #pragma unroll
        for (int nt = 0; nt < 2; ++nt) {
            int col_l = wn + nt * 16 + l15;
            #pragma unroll
            for (int i = 0; i < 4; ++i) {
                int row_l = wm + mt * 16 + lk * 4 + i;
                float v = acc[mt][nt][i];
                if (seg == 0) v *= QSCALE;
                sT[row_l * TSTRIDE + col_l] = f2bf(v);
                sp[nt] += v;
            }
        }
    __syncthreads();
    for (int c = tid; c < 512; c += 256) {
        int rl = c & 63, hh = c >> 6;
        const ushort* tp = sT + rl * TSTRIDE + hh;
        uint4 pk;
        pk.x = (unsigned)tp[0]  | ((unsigned)tp[8]  << 16);
        pk.y = (unsigned)tp[16] | ((unsigned)tp[24] << 16);
        pk.z = (unsigned)tp[32] | ((unsigned)tp[40] << 16);
        pk.w = (unsigned)tp[48] | ((unsigned)tp[56] << 16);
        int row = m0 + rl;
        if (seg == 0)
            *(uint4*)(qh + ((size_t)hh * NN + row) * HDIM + ddBase) = pk;
        else
            *(uint4*)(kvh + ((size_t)hh * NN + row) * 64 +
                      ((seg == 2) ? 32 : 0) + ddBase) = pk;
    }
    if (seg == 2) {
        int slot = ((wm >> 5) << 2) | lk;
        sRedS[slot][wn + l15]      = sp[0];
        sRedS[slot][wn + 16 + l15] = sp[1];
        __syncthreads();
        if (tid < 64) {
            float ss = 0.f;
            #pragma unroll
            for (int r = 0; r < 8; ++r) ss += sRedS[r][tid];
            vpart[(size_t)by * 256 + (n0 & 255) + tid] = ss;
        }
    }
}

// ---------------- bf16 MFMA GEMM (modes 0/1/2/3), XCD-swizzled -------------
// aMode 0: A bf16 [M,K]. aMode 1: A fp32 + on-load BN (scA/shA per col).
// aMode 2: A bf16 head-major [8][NN][32] (B k-permuted to match).
// storeMode 0: Cf fp32 (+resid). 1: Cb bf16 (relu opt).
//   3: Cf fp32, residual recomputed as yres*scR+shR (Cf may alias yres).
// bnstat: per-block col sum/sumsq partials -> bnps/bnpq [nby][256].
__global__ __launch_bounds__(256) void gemm_bf(
    const void* __restrict__ Aptr, const ushort* __restrict__ B,
    const float* __restrict__ scA, const float* __restrict__ shA,
    const float* __restrict__ resid,
    const float* yres, const float* __restrict__ scR, const float* __restrict__ shR,
    float* Cf, ushort* __restrict__ Cb,
    float* __restrict__ bnps, float* __restrict__ bnpq,
    int M, int Nn, int K, int aMode, int storeMode, int relu, int bnstat)
{
    __shared__ ushort As[64][LDP];
    __shared__ ushort Bs[64][LDP];
    __shared__ float sRedS[8][64];
    __shared__ float sRedQ[8][64];
    int tid = threadIdx.x;
    int lane = tid & 63, w = tid >> 6;
    int wm = (w >> 1) * 32, wn = (w & 1) * 32;
    int nbx = gridDim.x, nbyq = gridDim.y >> 3;
    int orig = blockIdx.y * nbx + blockIdx.x;
    int xcd = orig & 7, pos = orig >> 3;
    int by = xcd * nbyq + pos / nbx;
    int bx = pos % nbx;
    int m0 = by * 64, n0 = bx * 64;
    int l15 = lane & 15, lk = lane >> 4;
    int srow = tid >> 3;
    int scol = (tid & 7) * 8;

    f32x4 acc[2][2] = {};
    for (int k0 = 0; k0 < K; k0 += 64) {
        uint4 ga0, ga1, gb0, gb1;
        const ushort* Bg = B + (size_t)(n0 + srow) * K + scol + k0;
        gb0 = *(const uint4*)Bg;
        gb1 = *(const uint4*)(Bg + (size_t)32 * K);
        if (aMode == 0) {
            const ushort* Ag = (const ushort*)Aptr + (size_t)(m0 + srow) * K + scol + k0;
            ga0 = *(const uint4*)Ag;
            ga1 = *(const uint4*)(Ag + (size_t)32 * K);
        } else if (aMode == 2) {
            int c0 = k0 + scol;
            int hh = c0 >> 5, dd = c0 & 31;
            const ushort* Ag = (const ushort*)Aptr +
                ((size_t)hh * NN + m0 + srow) * HDIM + dd;
            ga0 = *(const uint4*)Ag;
            ga1 = *(const uint4*)(Ag + (size_t)32 * HDIM);
        } else {
            const float* Af = (const float*)Aptr + (size_t)(m0 + srow) * K + scol + k0;
            float4 sc0 = *(const float4*)(scA + k0 + scol);
            float4 sc1 = *(const float4*)(scA + k0 + scol + 4);
            float4 sh0 = *(const float4*)(shA + k0 + scol);
            float4 sh1 = *(const float4*)(shA + k0 + scol + 4);
            float4 a0 = *(const float4*)Af;
            float4 a1 = *(const float4*)(Af + 4);
            float4 b0 = *(const float4*)(Af + (size_t)32 * K);
            float4 b1 = *(const float4*)(Af + (size_t)32 * K + 4);
            ga0.x = (unsigned)f2bf(a0.x*sc0.x+sh0.x) | ((unsigned)f2bf(a0.y*sc0.y+sh0.y) << 16);
            ga0.y = (unsigned)f2bf(a0.z*sc0.z+sh0.z) | ((unsigned)f2bf(a0.w*sc0.w+sh0.w) << 16);
            ga0.z = (unsigned)f2bf(a1.x*sc1.x+sh1.x) | ((unsigned)f2bf(a1.y*sc1.y+sh1.y) << 16);
            ga0.w = (unsigned)f2bf(a1.z*sc1.z+sh1.z) | ((unsigned)f2bf(a1.w*sc1.w+sh1.w) << 16);
            ga1.x = (unsigned)f2bf(b0.x*sc0.x+sh0.x) | ((unsigned)f2bf(b0.y*sc0.y+sh0.y) << 16);
            ga1.y = (unsigned)f2bf(b0.z*sc0.z+sh0.z) | ((unsigned)f2bf(b0.w*sc0.w+sh0.w) << 16);
            ga1.z = (unsigned)f2bf(b1.x*sc1.x+sh1.x) | ((unsigned)f2bf(b1.y*sc1.y+sh1.y) << 16);
            ga1.w = (unsigned)f2bf(b1.z*sc1.z+sh1.z) | ((unsigned)f2bf(b1.w*sc1.w+sh1.w) << 16);
        }
        __syncthreads();
        *(uint4*)&As[srow][scol]      = ga0;
        *(uint4*)&As[srow + 32][scol] = ga1;
        *(uint4*)&Bs[srow][scol]      = gb0;
        *(uint4*)&Bs[srow + 32][scol] = gb1;
        __syncthreads();
        #pragma unroll
        for (int ks = 0; ks < 2; ++ks) {
            int kc = ks * 32 + lk * 8;
            short8 a0 = *(const short8*)&As[wm      + l15][kc];
            short8 a1 = *(const short8*)&As[wm + 16 + l15][kc];
            short8 b0 = *(const short8*)&Bs[wn      + l15][kc];
            short8 b1 = *(const short8*)&Bs[wn + 16 + l15][kc];
            acc[0][0] = __builtin_amdgcn_mfma_f32_16x16x32_bf16(a0, b0, acc[0][0], 0, 0, 0);
            acc[0][1] = __builtin_amdgcn_mfma_f32_16x16x32_bf16(a0, b1, acc[0][1], 0, 0, 0);
            acc[1][0] = __builtin_amdgcn_mfma_f32_16x16x32_bf16(a1, b0, acc[1][0], 0, 0, 0);
            acc[1][1] = __builtin_amdgcn_mfma_f32_16x16x32_bf16(a1, b1, acc[1][1], 0, 0, 0);
        }
    }

    float sp[2] = {0.f, 0.f}, qp[2] = {0.f, 0.f};
    #pragma unroll
    for (int mt = 0; mt < 2; ++mt) {
        #pragma unroll
        for (int nt = 0; nt < 2; ++nt) {
            int col = n0 + wn + nt * 16 + l15;
            #pragma unroll
            for (int i = 0; i < 4; ++i) {
                int row = m0 + wm + mt * 16 + lk * 4 + i;
                float v = acc[mt][nt][i];
                if (storeMode == 0) {
                    if (resid) v += resid[(size_t)row * Nn + col];
                    Cf[(size_t)row * Nn + col] = v;
                } else if (storeMode == 1) {
                    if (relu) v = fmaxf(v, 0.f);
                    Cb[(size_t)row * Nn + col] = f2bf(v);
                } else { // 3
                    v += yres[(size_t)row * Nn + col] * scR[col] + shR[col];
                    Cf[(size_t)row * Nn + col] = v;
                }
                if (bnstat) { sp[nt] += v; qp[nt] += v * v; }
            }
        }
    }
    if (bnstat) {
        int slot = ((wm >> 5) << 2) | lk;
        sRedS[slot][wn + l15]      = sp[0];
        sRedQ[slot][wn + l15]      = qp[0];
        sRedS[slot][wn + 16 + l15] = sp[1];
        sRedQ[slot][wn + 16 + l15] = qp[1];
        __syncthreads();
        if (tid < 64) {
            float ss = 0.f, qq = 0.f;
            #pragma unroll
            for (int r = 0; r < 8; ++r) { ss += sRedS[r][tid]; qq += sRedQ[r][tid]; }
            bnps[(size_t)by * DIM + n0 + tid] = ss;
            bnpq[(size_t)by * DIM + n0 + tid] = qq;
        }
    }
}

// ---------------- BN stats final: 64 partials -> scale/shift ---------------
__global__ __launch_bounds__(1024) void colreduce_final2(
    const float* __restrict__ ps, const float* __restrict__ pq,
    const float* __restrict__ g, const float* __restrict__ bsh,
    float* __restrict__ scale, float* __restrict__ shift)
{
    __shared__ float rs_[4][256], rq_[4][256];
    int t = threadIdx.x;
    int c = t & 255, qd = t >> 8;
    float s = 0.f, q = 0.f;
    for (int b = qd; b < 64; b += 4) {
        s += ps[b * DIM + c];
        q += pq[b * DIM + c];
    }
    rs_[qd][c] = s; rq_[qd][c] = q;
    __syncthreads();
    if (qd == 0) {
        s = rs_[0][c] + rs_[1][c] + rs_[2][c] + rs_[3][c];
        q = rq_[0][c] + rq_[1][c] + rq_[2][c] + rq_[3][c];
        float m = s * (1.f / NN);
        float var = q * (1.f / NN) - m * m;
        float rstd = rsqrtf(var + EPS_BN);
        float sc = rstd * g[c];
        scale[c] = sc;
        shift[c] = bsh[c] - m * sc;
    }
}

__global__ __launch_bounds__(256) void bn_apply_fin(
    const float* __restrict__ x, const float* __restrict__ scale,
    const float* __restrict__ shift, float* __restrict__ out)
{
    int tid = threadIdx.x;
    size_t i = (size_t)blockIdx.x * 1024 + (size_t)tid * 4;
    int c = (tid * 4) & 255;
    float4 v = *(const float4*)(x + i);
    float4 sc = *(const float4*)(scale + c);
    float4 sh = *(const float4*)(shift + c);
    float4 r;
    r.x = v.x * sc.x + sh.x;
    r.y = v.y * sc.y + sh.y;
    r.z = v.z * sc.z + sh.z;
    r.w = v.w * sc.w + sh.w;
    *(float4*)(out + i) = r;
}

// ---------------- head-partitioned sparse masked attention -----------------
// Block b: head hH = b&7 (-> XCD b&7), rows rg*8..rg*8+7. Per-XCD working
// set = one head's q+kv (~768 KB) -> L2-resident. No-max-shift softmax.
// Each block reduces its own head's vsum slice from vpart (no finisher
// kernel, no cross-block sync — vpart written by the prior dispatch).
__global__ __launch_bounds__(256) void attn3(
    const ushort* __restrict__ qh, const ushort* __restrict__ kvh,
    const float* __restrict__ vpart,
    const unsigned* __restrict__ packed, const int* __restrict__ cnt,
    ushort* __restrict__ outh)
{
    __shared__ float    sQ[8][32];
    __shared__ unsigned sPk[8][CAP];
    __shared__ float    sS[8][CAP];
    __shared__ float    sRd[8];
    __shared__ float    sVred[8][32];
    __shared__ float    sVs[32];

    int tid = threadIdx.x, b = blockIdx.x;
    int hH = b & 7, rg = b >> 3;
    int r = tid >> 5, l = tid & 31;
    int n = rg * 8 + r;
    int nnz = cnt[n];

    sQ[r][l] = bf2f(qh[((size_t)hH * NN + n) * HDIM + l]);
    for (int j = l; j < nnz; j += 32) sPk[r][j] = packed[n * CAP + j];
    // per-block vsum reduction: head hH's columns are c = hH + 8*d
    {
        float vs = 0.f;
        #pragma unroll
        for (int bb = r; bb < 64; bb += 8)
            vs += vpart[(size_t)bb * 256 + hH + 8 * l];
        sVred[r][l] = vs;
    }
    __syncthreads();
    if (r == 0) {
        float t = 0.f;
        #pragma unroll
        for (int i = 0; i < 8; ++i) t += sVred[i][l];
        sVs[l] = t;
    }

    // phase 1: scores + weights + denom (32 lanes split j within the row)
    float4 qreg[8];
    #pragma unroll
    for (int t = 0; t < 8; ++t) qreg[t] = ((const float4*)sQ[r])[t];
    float lsum = 0.0f;
    for (int j = l; j < nnz; j += 32) {
        unsigned pk = sPk[r][j];
        int m = pk & 0xFFFF;
        float a = bfhi(pk);
        const uint4* kp = (const uint4*)(kvh + ((size_t)hH * NN + m) * 64);
        uint4 k0 = kp[0], k1 = kp[1], k2 = kp[2], k3 = kp[3];
        float s =
            bflo(k0.x)*qreg[0].x + bfhi(k0.x)*qreg[0].y +
            bflo(k0.y)*qreg[0].z + bfhi(k0.y)*qreg[0].w +
            bflo(k0.z)*qreg[1].x + bfhi(k0.z)*qreg[1].y +
            bflo(k0.w)*qreg[1].z + bfhi(k0.w)*qreg[1].w +
            bflo(k1.x)*qreg[2].x + bfhi(k1.x)*qreg[2].y +
            bflo(k1.y)*qreg[2].z + bfhi(k1.y)*qreg[2].w +
            bflo(k1.z)*qreg[3].x + bfhi(k1.z)*qreg[3].y +
            bflo(k1.w)*qreg[3].z + bfhi(k1.w)*qreg[3].w +
            bflo(k2.x)*qreg[4].x + bfhi(k2.x)*qreg[4].y +
            bflo(k2.y)*qreg[4].z + bfhi(k2.y)*qreg[4].w +
            bflo(k2.z)*qreg[5].x + bfhi(k2.z)*qreg[5].y +
            bflo(k2.w)*qreg[5].z + bfhi(k2.w)*qreg[5].w +
            bflo(k3.x)*qreg[6].x + bfhi(k3.x)*qreg[6].y +
            bflo(k3.y)*qreg[6].z + bfhi(k3.y)*qreg[6].w +
            bflo(k3.z)*qreg[7].x + bfhi(k3.z)*qreg[7].y +
            bflo(k3.w)*qreg[7].z + bfhi(k3.w)*qreg[7].w;
        s *= a;
        float ww = __expf(s);
        sS[r][j] = ww - 1.0f;
        lsum += ww;
    }
    #pragma unroll
    for (int o = 16; o > 0; o >>= 1) lsum += __shfl_xor(lsum, o, 32);
    if (l == 0) sRd[r] = 1.0f / (lsum + (float)(NN - nnz));
    __syncthreads();   // covers sRd and sVs

    // phase 2: lane = (jsub = l>>3, dq = l&7); 4-way j split, uint2 gathers
    int jsub = l >> 3, dq = l & 7;
    const ushort* vbase = kvh + (size_t)hH * NN * 64 + 32 + dq * 4;
    float a0 = 0.f, a1 = 0.f, a2 = 0.f, a3 = 0.f;
    for (int j = jsub; j < nnz; j += 4) {
        float ww = sS[r][j];
        int m = sPk[r][j] & 0xFFFF;
        uint2 vv = *(const uint2*)(vbase + (size_t)m * 64);
        a0 += ww * bflo(vv.x); a1 += ww * bfhi(vv.x);
        a2 += ww * bflo(vv.y); a3 += ww * bfhi(vv.y);
    }
    #pragma unroll
    for (int o = 8; o < 32; o <<= 1) {
        a0 += __shfl_xor(a0, o, 32);
        a1 += __shfl_xor(a1, o, 32);
        a2 += __shfl_xor(a2, o, 32);
        a3 += __shfl_xor(a3, o, 32);
    }
    if (jsub == 0) {
        float rd = sRd[r];
        int d0 = dq * 4;
        float r0 = (a0 + sVs[d0 + 0]) * rd;
        float r1 = (a1 + sVs[d0 + 1]) * rd;
        float r2 = (a2 + sVs[d0 + 2]) * rd;
        float r3 = (a3 + sVs[d0 + 3]) * rd;
        uint2 st;
        st.x = (unsigned)f2bf(r0) | ((unsigned)f2bf(r1) << 16);
        st.y = (unsigned)f2bf(r2) | ((unsigned)f2bf(r3) << 16);
        *(uint2*)(outh + ((size_t)hH * NN + n) * HDIM + d0) = st;
    }
}

// ---------------------------------------------------------------------------
extern "C" void kernel_launch(void* const* d_in, const int* in_sizes, int n_in,
                              void* d_out, int out_size, void* d_ws, size_t ws_size,
                              hipStream_t stream)
{
    const float* A  = (const float*)d_in[0];
    const float* h  = (const float*)d_in[1];
    const float* Wq = (const float*)d_in[2];
    const float* Wk = (const float*)d_in[3];
    const float* Wv = (const float*)d_in[4];
    const float* Wo = (const float*)d_in[5];
    const float* g1 = (const float*)d_in[6];
    const float* b1 = (const float*)d_in[7];
    const float* g2 = (const float*)d_in[8];
    const float* b2 = (const float*)d_in[9];
    const float* W1 = (const float*)d_in[10];
    const float* W2 = (const float*)d_in[11];
    float* out = (float*)d_out;
    char* w = (char*)d_ws;

    unsigned* packed = (unsigned*)(w);           // [0,2M)  nz lists
    int*    nzcnt  = (int*)(w + 2 * MB);
    ushort* h_bf   = (ushort*)(w + 3 * MB);      // 2 MB
    ushort* wqkv   = (ushort*)(w + 5 * MB);      // 384 KB
    ushort* wo_b   = (ushort*)(w + 5 * MB + 384 * 1024);   // k-permuted Wo
    ushort* w1_b   = (ushort*)(w + 5 * MB + 512 * 1024);
    ushort* w2_b   = (ushort*)(w + 5 * MB + 768 * 1024);
    ushort* qh_bf  = (ushort*)(w + 6 * MB);      // 2 MB [8][4096][32]
    ushort* kvh    = (ushort*)(w + 8 * MB);      // 4 MB [8][4096][64] k|v
    ushort* ao_hb  = (ushort*)(w + 12 * MB);     // 2 MB [8][4096][32] head-major
    float*  y      = (float*)(w + 14 * MB);      // 4 MB
    ushort* t_bf   = (ushort*)(w + 18 * MB);     // 4 MB FFN hidden
    float*  vpart  = (float*)(w + 22 * MB);      // 64 KB [64][256]
    float*  bnps   = (float*)(w + 23 * MB);      // 64 KB [64][256]
    float*  bnpq   = (float*)(w + 23 * MB + 64 * 1024);
    float*  scale1 = (float*)(w + 24 * MB);
    float*  shift1 = scale1 + 256;
    float*  scale2 = scale1 + 512;
    float*  shift2 = scale1 + 768;

    dim3 blk(256);

    // 1: bf16 conversions (Wo k-permuted)
    convert_bf<<<768, blk, 0, stream>>>(h, Wq, Wk, Wv, Wo, W1, W2,
        h_bf, wqkv, wqkv + 65536, wqkv + 131072, wo_b, w1_b, w2_b);
    // 2: fused QKV gemm + A nz-scan
    qkv_ascan<<<4864, blk, 0, stream>>>(h_bf, wqkv, qh_bf, kvh, vpart,
                                        A, packed, nzcnt);
    // 3: head-partitioned attention (per-block vsum reduce) -> ao_hb
    attn3<<<NN, blk, 0, stream>>>(qh_bf, kvh, vpart, packed, nzcnt, ao_hb);
    // 4: Wo projection (head-major A, permuted Wo) + residual(h) -> y + BN1 partials
    gemm_bf<<<dim3(4, 64), blk, 0, stream>>>(ao_hb, wo_b,
        nullptr, nullptr, h, nullptr, nullptr, nullptr,
        y, nullptr, bnps, bnpq, NN, DIM, DIM, 2, 0, 0, 1);
    // 5: BN1 -> scale1/shift1
    colreduce_final2<<<1, dim3(1024), 0, stream>>>(bnps, bnpq, g1, b1, scale1, shift1);
    // 6: FFN1 with BN1 applied on A-load, relu, bf16 out
    gemm_bf<<<dim3(8, 64), blk, 0, stream>>>(y, w1_b,
        scale1, shift1, nullptr, nullptr, nullptr, nullptr,
        nullptr, t_bf, nullptr, nullptr, NN, DFF, DIM, 1, 1, 1, 0);
    // 7: FFN2 + recomputed BN1 residual, in-place on y, with BN2 stat partials
    gemm_bf<<<dim3(4, 64), blk, 0, stream>>>(t_bf, w2_b,
        nullptr, nullptr, nullptr, y, scale1, shift1,
        y, nullptr, bnps, bnpq, NN, DIM, DFF, 0, 3, 0, 1);
    // 8: BN2 -> scale2/shift2
    colreduce_final2<<<1, dim3(1024), 0, stream>>>(bnps, bnpq, g2, b2, scale2, shift2);
    // 9: BN2 apply -> d_out
    bn_apply_fin<<<1024, blk, 0, stream>>>(y, scale2, shift2, out);
}

// Round 12
// 103.147 us; speedup vs baseline: 1.5906x; 1.0051x over previous
//
#include <hip/hip_runtime.h>
#include <math.h>

#define NN 4096        // nodes
#define DIM 256        // hidden
#define NHEAD 8
#define HDIM 32
#define DFF 512
#define CAP 128        // max nonzeros per row (mean ~41, max ~75 at p=.01)
#define EPS_BN 1e-5f
#define QSCALE 0.0625f // D^-0.5
#define MB (1u << 20)

typedef __attribute__((ext_vector_type(8))) short short8;
typedef __attribute__((ext_vector_type(4))) float f32x4;

__device__ inline ushort f2bf(float x) {   // RNE float->bf16
    unsigned u = __builtin_bit_cast(unsigned, x);
    unsigned r = u + 0x7FFF + ((u >> 16) & 1);
    return (ushort)(r >> 16);
}
__device__ inline float bf2f(ushort u) {
    return __builtin_bit_cast(float, (unsigned)u << 16);
}
__device__ inline float bflo(unsigned u) { return __builtin_bit_cast(float, u << 16); }
__device__ inline float bfhi(unsigned u) { return __builtin_bit_cast(float, u & 0xFFFF0000u); }

// ---------------- convert: fp32 -> bf16 (h + all weights) ------------------
// Wo (blocks 608..639) stored with k-columns permuted to [h*32+d] order.
__global__ __launch_bounds__(256) void convert_bf(
    const float* __restrict__ s0, const float* __restrict__ s1,
    const float* __restrict__ s2, const float* __restrict__ s3,
    const float* __restrict__ s4, const float* __restrict__ s5,
    const float* __restrict__ s6,
    ushort* d0, ushort* d1, ushort* d2, ushort* d3,
    ushort* d4, ushort* d5, ushort* d6)
{
    int b = blockIdx.x, tid = threadIdx.x;
    if (b >= 608 && b < 640) {
        int off = b - 608;
        int row = off * 8 + (tid >> 5), t = tid & 31;
        int hh = t >> 2, dd0 = (t & 3) * 8;
        const float* src = s4 + (size_t)row * 256 + hh;
        ushort tmp[8];
        #pragma unroll
        for (int i = 0; i < 8; ++i) tmp[i] = f2bf(src[(size_t)(dd0 + i) * 8]);
        uint4 u;
        u.x = (unsigned)tmp[0] | ((unsigned)tmp[1] << 16);
        u.y = (unsigned)tmp[2] | ((unsigned)tmp[3] << 16);
        u.z = (unsigned)tmp[4] | ((unsigned)tmp[5] << 16);
        u.w = (unsigned)tmp[6] | ((unsigned)tmp[7] << 16);
        *(uint4*)(d4 + (size_t)row * 256 + hh * 32 + dd0) = u;
        return;
    }
    const float* s; ushort* d; int off;
    if      (b < 512) { s = s0; d = d0; off = b; }
    else if (b < 544) { s = s1; d = d1; off = b - 512; }
    else if (b < 576) { s = s2; d = d2; off = b - 544; }
    else if (b < 608) { s = s3; d = d3; off = b - 576; }
    else if (b < 704) { s = s5; d = d5; off = b - 640; }
    else              { s = s6; d = d6; off = b - 704; }
    size_t base = (size_t)off * 2048 + (size_t)tid * 8;
    float4 f0 = *(const float4*)(s + base);
    float4 f1 = *(const float4*)(s + base + 4);
    uint4 u;
    u.x = (unsigned)f2bf(f0.x) | ((unsigned)f2bf(f0.y) << 16);
    u.y = (unsigned)f2bf(f0.z) | ((unsigned)f2bf(f0.w) << 16);
    u.z = (unsigned)f2bf(f1.x) | ((unsigned)f2bf(f1.y) << 16);
    u.w = (unsigned)f2bf(f1.z) | ((unsigned)f2bf(f1.w) << 16);
    *(uint4*)(d + base) = u;
}

// ---------------- fused: QKV gemm (blocks 0..767) + A nz-scan (768..4863) --
#define LDP 88
#define TSTRIDE 74
__global__ __launch_bounds__(256) void qkv_ascan(
    const ushort* __restrict__ Ah, const ushort* __restrict__ B,
    ushort* __restrict__ qh, ushort* __restrict__ kvh,
    float* __restrict__ vpart,
    const float* __restrict__ Araw, unsigned* __restrict__ packed,
    int* __restrict__ cnt)
{
    __shared__ ushort As[64][LDP];
    __shared__ ushort Bs[64][LDP];
    __shared__ float sRedS[8][64];
    int b = blockIdx.x, tid = threadIdx.x;

    if (b >= 768) {
        int* scan = (int*)&As[0][0];
        int n = b - 768;
        const float* row = Araw + (size_t)n * NN;
        float4 vals[4];
        int c = 0;
        #pragma unroll
        for (int i = 0; i < 4; ++i) {
            vals[i] = *(const float4*)(row + i * 1024 + tid * 4);
            c += (vals[i].x != 0.f) + (vals[i].y != 0.f)
               + (vals[i].z != 0.f) + (vals[i].w != 0.f);
        }
        scan[tid] = c;
        __syncthreads();
        for (int off = 1; off < 256; off <<= 1) {
            int t = (tid >= off) ? scan[tid - off] : 0;
            __syncthreads();
            scan[tid] += t;
            __syncthreads();
        }
        int pos = scan[tid] - c;       // exclusive prefix
        int total = scan[255];
        #pragma unroll
        for (int i = 0; i < 4; ++i) {
            int cb = i * 1024 + tid * 4;
            float4 v = vals[i];
            if (v.x != 0.f && pos < CAP) { packed[n*CAP+pos] = ((unsigned)f2bf(v.x) << 16) | (unsigned)cb;       ++pos; }
            if (v.y != 0.f && pos < CAP) { packed[n*CAP+pos] = ((unsigned)f2bf(v.y) << 16) | (unsigned)(cb + 1); ++pos; }
            if (v.z != 0.f && pos < CAP) { packed[n*CAP+pos] = ((unsigned)f2bf(v.z) << 16) | (unsigned)(cb + 2); ++pos; }
            if (v.w != 0.f && pos < CAP) { packed[n*CAP+pos] = ((unsigned)f2bf(v.w) << 16) | (unsigned)(cb + 3); ++pos; }
        }
        if (tid == 0) cnt[n] = min(total, CAP);
        return;
    }

    int lane = tid & 63, w = tid >> 6;
    int wm = (w >> 1) * 32, wn = (w & 1) * 32;
    int xcd = b & 7, pos = b >> 3;
    int by = xcd * 8 + pos / 12;
    int bx = pos % 12;
    int m0 = by * 64, n0 = bx * 64;
    int l15 = lane & 15, lk = lane >> 4;
    int srow = tid >> 3;
    int scol = (tid & 7) * 8;

    f32x4 acc[2][2] = {};
    for (int k0 = 0; k0 < DIM; k0 += 64) {
        const ushort* Bg = B + (size_t)(n0 + srow) * DIM + scol + k0;
        uint4 gb0 = *(const uint4*)Bg;
        uint4 gb1 = *(const uint4*)(Bg + (size_t)32 * DIM);
        const ushort* Ag = Ah + (size_t)(m0 + srow) * DIM + scol + k0;
        uint4 ga0 = *(const uint4*)Ag;
        uint4 ga1 = *(const uint4*)(Ag + (size_t)32 * DIM);
        __syncthreads();
        *(uint4*)&As[srow][scol]      = ga0;
        *(uint4*)&As[srow + 32][scol] = ga1;
        *(uint4*)&Bs[srow][scol]      = gb0;
        *(uint4*)&Bs[srow + 32][scol] = gb1;
        __syncthreads();
        #pragma unroll
        for (int ks = 0; ks < 2; ++ks) {
            int kc = ks * 32 + lk * 8;
            short8 a0 = *(const short8*)&As[wm      + l15][kc];
            short8 a1 = *(const short8*)&As[wm + 16 + l15][kc];
            short8 b0 = *(const short8*)&Bs[wn      + l15][kc];
            short8 b1 = *(const short8*)&Bs[wn + 16 + l15][kc];
            acc[0][0] = __builtin_amdgcn_mfma_f32_16x16x32_bf16(a0, b0, acc[0][0], 0, 0, 0);
            acc[0][1] = __builtin_amdgcn_mfma_f32_16x16x32_bf16(a0, b1, acc[0][1], 0, 0, 0);
            acc[1][0] = __builtin_amdgcn_mfma_f32_16x16x32_bf16(a1, b0, acc[1][0], 0, 0, 0);
            acc[1][1] = __builtin_amdgcn_mfma_f32_16x16x32_bf16(a1, b1, acc[1][1], 0, 0, 0);
        }
    }
    ushort* sT = &As[0][0];
    int seg = n0 >> 8, ddBase = (n0 & 255) >> 3;
    float sp[2] = {0.f, 0.f};
    __syncthreads();
    #pragma unroll
    for (int mt = 0; mt < 2; ++mt)
        #pragma unroll
        for (int nt = 0; nt < 2; ++nt) {
            int col_l = wn + nt * 16 + l15;
            #pragma unroll
            for (int i = 0; i < 4; ++i) {
                int row_l = wm + mt * 16 + lk * 4 + i;
                float v = acc[mt][nt][i];
                if (seg == 0) v *= QSCALE;
                sT[row_l * TSTRIDE + col_l] = f2bf(v);
                sp[nt] += v;
            }
        }
    __syncthreads();
    for (int c = tid; c < 512; c += 256) {
        int rl = c & 63, hh = c >> 6;
        const ushort* tp = sT + rl * TSTRIDE + hh;
        uint4 pk;
        pk.x = (unsigned)tp[0]  | ((unsigned)tp[8]  << 16);
        pk.y = (unsigned)tp[16] | ((unsigned)tp[24] << 16);
        pk.z = (unsigned)tp[32] | ((unsigned)tp[40] << 16);
        pk.w = (unsigned)tp[48] | ((unsigned)tp[56] << 16);
        int row = m0 + rl;
        if (seg == 0)
            *(uint4*)(qh + ((size_t)hh * NN + row) * HDIM + ddBase) = pk;
        else
            *(uint4*)(kvh + ((size_t)hh * NN + row) * 64 +
                      ((seg == 2) ? 32 : 0) + ddBase) = pk;
    }
    if (seg == 2) {
        int slot = ((wm >> 5) << 2) | lk;
        sRedS[slot][wn + l15]      = sp[0];
        sRedS[slot][wn + 16 + l15] = sp[1];
        __syncthreads();
        if (tid < 64) {
            float ss = 0.f;
            #pragma unroll
            for (int r = 0; r < 8; ++r) ss += sRedS[r][tid];
            vpart[(size_t)by * 256 + (n0 & 255) + tid] = ss;
        }
    }
}

// ---------------- vsum final: 64 coalesced partials -> vsumh[h][d] ---------
__global__ __launch_bounds__(256) void vsum_final(
    const float* __restrict__ vpart, float* __restrict__ vsumh)
{
    int c = threadIdx.x;
    float s = 0.f;
    #pragma unroll 8
    for (int b = 0; b < 64; ++b) s += vpart[(size_t)b * 256 + c];
    vsumh[(c & 7) * HDIM + (c >> 3)] = s;
}

// ---------------- bf16 MFMA GEMM (modes 0/1/2/3), XCD-swizzled -------------
__global__ __launch_bounds__(256) void gemm_bf(
    const void* __restrict__ Aptr, const ushort* __restrict__ B,
    const float* __restrict__ scA, const float* __restrict__ shA,
    const float* __restrict__ resid,
    const float* yres, const float* __restrict__ scR, const float* __restrict__ shR,
    float* Cf, ushort* __restrict__ Cb,
    float* __restrict__ bnps, float* __restrict__ bnpq,
    int M, int Nn, int K, int aMode, int storeMode, int relu, int bnstat)
{
    __shared__ ushort As[64][LDP];
    __shared__ ushort Bs[64][LDP];
    __shared__ float sRedS[8][64];
    __shared__ float sRedQ[8][64];
    int tid = threadIdx.x;
    int lane = tid & 63, w = tid >> 6;
    int wm = (w >> 1) * 32, wn = (w & 1) * 32;
    int nbx = gridDim.x, nbyq = gridDim.y >> 3;
    int orig = blockIdx.y * nbx + blockIdx.x;
    int xcd = orig & 7, pos = orig >> 3;
    int by = xcd * nbyq + pos / nbx;
    int bx = pos % nbx;
    int m0 = by * 64, n0 = bx * 64;
    int l15 = lane & 15, lk = lane >> 4;
    int srow = tid >> 3;
    int scol = (tid & 7) * 8;

    f32x4 acc[2][2] = {};
    for (int k0 = 0; k0 < K; k0 += 64) {
        uint4 ga0, ga1, gb0, gb1;
        const ushort* Bg = B + (size_t)(n0 + srow) * K + scol + k0;
        gb0 = *(const uint4*)Bg;
        gb1 = *(const uint4*)(Bg + (size_t)32 * K);
        if (aMode == 0) {
            const ushort* Ag = (const ushort*)Aptr + (size_t)(m0 + srow) * K + scol + k0;
            ga0 = *(const uint4*)Ag;
            ga1 = *(const uint4*)(Ag + (size_t)32 * K);
        } else if (aMode == 2) {
            int c0 = k0 + scol;
            int hh = c0 >> 5, dd = c0 & 31;
            const ushort* Ag = (const ushort*)Aptr +
                ((size_t)hh * NN + m0 + srow) * HDIM + dd;
            ga0 = *(const uint4*)Ag;
            ga1 = *(const uint4*)(Ag + (size_t)32 * HDIM);
        } else {
            const float* Af = (const float*)Aptr + (size_t)(m0 + srow) * K + scol + k0;
            float4 sc0 = *(const float4*)(scA + k0 + scol);
            float4 sc1 = *(const float4*)(scA + k0 + scol + 4);
            float4 sh0 = *(const float4*)(shA + k0 + scol);
            float4 sh1 = *(const float4*)(shA + k0 + scol + 4);
            float4 a0 = *(const float4*)Af;
            float4 a1 = *(const float4*)(Af + 4);
            float4 b0 = *(const float4*)(Af + (size_t)32 * K);
            float4 b1 = *(const float4*)(Af + (size_t)32 * K + 4);
            ga0.x = (unsigned)f2bf(a0.x*sc0.x+sh0.x) | ((unsigned)f2bf(a0.y*sc0.y+sh0.y) << 16);
            ga0.y = (unsigned)f2bf(a0.z*sc0.z+sh0.z) | ((unsigned)f2bf(a0.w*sc0.w+sh0.w) << 16);
            ga0.z = (unsigned)f2bf(a1.x*sc1.x+sh1.x) | ((unsigned)f2bf(a1.y*sc1.y+sh1.y) << 16);
            ga0.w = (unsigned)f2bf(a1.z*sc1.z+sh1.z) | ((unsigned)f2bf(a1.w*sc1.w+sh1.w) << 16);
            ga1.x = (unsigned)f2bf(b0.x*sc0.x+sh0.x) | ((unsigned)f2bf(b0.y*sc0.y+sh0.y) << 16);
            ga1.y = (unsigned)f2bf(b0.z*sc0.z+sh0.z) | ((unsigned)f2bf(b0.w*sc0.w+sh0.w) << 16);
            ga1.z = (unsigned)f2bf(b1.x*sc1.x+sh1.x) | ((unsigned)f2bf(b1.y*sc1.y+sh1.y) << 16);
            ga1.w = (unsigned)f2bf(b1.z*sc1.z+sh1.z) | ((unsigned)f2bf(b1.w*sc1.w+sh1.w) << 16);
        }
        __syncthreads();
        *(uint4*)&As[srow][scol]      = ga0;
        *(uint4*)&As[srow + 32][scol] = ga1;
        *(uint4*)&Bs[srow][scol]      = gb0;
        *(uint4*)&Bs[srow + 32][scol] = gb1;
        __syncthreads();
        #pragma unroll
        for (int ks = 0; ks < 2; ++ks) {
            int kc = ks * 32 + lk * 8;
            short8 a0 = *(const short8*)&As[wm      + l15][kc];
            short8 a1 = *(const short8*)&As[wm + 16 + l15][kc];
            short8 b0 = *(const short8*)&Bs[wn      + l15][kc];
            short8 b1 = *(const short8*)&Bs[wn + 16 + l15][kc];
            acc[0][0] = __builtin_amdgcn_mfma_f32_16x16x32_bf16(a0, b0, acc[0][0], 0, 0, 0);
            acc[0][1] = __builtin_amdgcn_mfma_f32_16x16x32_bf16(a0, b1, acc[0][1], 0, 0, 0);
            acc[1][0] = __builtin_amdgcn_mfma_f32_16x16x32_bf16(a1, b0, acc[1][0], 0, 0, 0);
            acc[1][1] = __builtin_amdgcn_mfma_f32_16x16x32_bf16(a1, b1, acc[1][1], 0, 0, 0);
        }
    }

    float sp[2] = {0.f, 0.f}, qp[2] = {0.f, 0.f};
    #pragma unroll
    for (int mt = 0; mt < 2; ++mt) {
        #pragma unroll
        for (int nt = 0; nt < 2; ++nt) {
            int col = n0 + wn + nt * 16 + l15;
            #pragma unroll
            for (int i = 0; i < 4; ++i) {
                int row = m0 + wm + mt * 16 + lk * 4 + i;
                float v = acc[mt][nt][i];
                if (storeMode == 0) {
                    if (resid) v += resid[(size_t)row * Nn + col];
                    Cf[(size_t)row * Nn + col] = v;
                } else if (storeMode == 1) {
                    if (relu) v = fmaxf(v, 0.f);
                    Cb[(size_t)row * Nn + col] = f2bf(v);
                } else { // 3
                    v += yres[(size_t)row * Nn + col] * scR[col] + shR[col];
                    Cf[(size_t)row * Nn + col] = v;
                }
                if (bnstat) { sp[nt] += v; qp[nt] += v * v; }
            }
        }
    }
    if (bnstat) {
        int slot = ((wm >> 5) << 2) | lk;
        sRedS[slot][wn + l15]      = sp[0];
        sRedQ[slot][wn + l15]      = qp[0];
        sRedS[slot][wn + 16 + l15] = sp[1];
        sRedQ[slot][wn + 16 + l15] = qp[1];
        __syncthreads();
        if (tid < 64) {
            float ss = 0.f, qq = 0.f;
            #pragma unroll
            for (int r = 0; r < 8; ++r) { ss += sRedS[r][tid]; qq += sRedQ[r][tid]; }
            bnps[(size_t)by * DIM + n0 + tid] = ss;
            bnpq[(size_t)by * DIM + n0 + tid] = qq;
        }
    }
}

// ---------------- BN stats final: 64 partials -> scale/shift ---------------
__global__ __launch_bounds__(1024) void colreduce_final2(
    const float* __restrict__ ps, const float* __restrict__ pq,
    const float* __restrict__ g, const float* __restrict__ bsh,
    float* __restrict__ scale, float* __restrict__ shift)
{
    __shared__ float rs_[4][256], rq_[4][256];
    int t = threadIdx.x;
    int c = t & 255, qd = t >> 8;
    float s = 0.f, q = 0.f;
    for (int b = qd; b < 64; b += 4) {
        s += ps[b * DIM + c];
        q += pq[b * DIM + c];
    }
    rs_[qd][c] = s; rq_[qd][c] = q;
    __syncthreads();
    if (qd == 0) {
        s = rs_[0][c] + rs_[1][c] + rs_[2][c] + rs_[3][c];
        q = rq_[0][c] + rq_[1][c] + rq_[2][c] + rq_[3][c];
        float m = s * (1.f / NN);
        float var = q * (1.f / NN) - m * m;
        float rstd = rsqrtf(var + EPS_BN);
        float sc = rstd * g[c];
        scale[c] = sc;
        shift[c] = bsh[c] - m * sc;
    }
}

__global__ __launch_bounds__(256) void bn_apply_fin(
    const float* __restrict__ x, const float* __restrict__ scale,
    const float* __restrict__ shift, float* __restrict__ out)
{
    int tid = threadIdx.x;
    size_t i = (size_t)blockIdx.x * 1024 + (size_t)tid * 4;
    int c = (tid * 4) & 255;
    float4 v = *(const float4*)(x + i);
    float4 sc = *(const float4*)(scale + c);
    float4 sh = *(const float4*)(shift + c);
    float4 r;
    r.x = v.x * sc.x + sh.x;
    r.y = v.y * sc.y + sh.y;
    r.z = v.z * sc.z + sh.z;
    r.w = v.w * sc.w + sh.w;
    *(float4*)(out + i) = r;
}

// ---------------- head-partitioned attention, fused single-pass ------------
// Block b: head hH = b&7 (-> XCD b&7), rows rg*8..rg*8+7, 32 lanes/row.
// Each lane: for its j's, load the FULL 128B kv row ONCE, compute its own
// score ww = exp(q.k*a) (lane-local!), accumulate (ww-1)*v into 32 regs.
// Cross-lane: scalar denom shfl-reduce + 32-float LDS transpose reduce
// (padded, conflict-free, two row-batches to cap LDS).
__global__ __launch_bounds__(256) void attn4(
    const ushort* __restrict__ qh, const ushort* __restrict__ kvh,
    const float* __restrict__ vsumh,
    const unsigned* __restrict__ packed, const int* __restrict__ cnt,
    ushort* __restrict__ outh)
{
    __shared__ unsigned sQp[8][16];      // packed bf16 q rows (512 B)
    __shared__ unsigned sPk[8][CAP];     // 4 KB
    __shared__ float    sRd[8];
    __shared__ float    sRed[4][32][33]; // 16.9 KB transpose buffer

    int tid = threadIdx.x, b = blockIdx.x;
    int hH = b & 7, rg = b >> 3;
    int r = tid >> 5, l = tid & 31;
    int n = rg * 8 + r;
    int nnz = cnt[n];

    if (l < 16)
        sQp[r][l] = ((const unsigned*)(qh + ((size_t)hH * NN + n) * HDIM))[l];
    for (int j = l; j < nnz; j += 32) sPk[r][j] = packed[n * CAP + j];
    __syncthreads();

    float acc[32];
    #pragma unroll
    for (int i = 0; i < 32; ++i) acc[i] = 0.f;
    float lsum = 0.f;

    for (int j = l; j < nnz; j += 32) {
        unsigned pk = sPk[r][j];
        int m = pk & 0xFFFF;
        float a = bfhi(pk);
        const uint4* kp = (const uint4*)(kvh + ((size_t)hH * NN + m) * 64);
        uint4 k0 = kp[0], k1 = kp[1], k2 = kp[2], k3 = kp[3];  // k: 64B
        uint4 v0 = kp[4], v1 = kp[5], v2 = kp[6], v3 = kp[7];  // v: 64B
        const unsigned* q = sQp[r];
        float s =
            bflo(k0.x)*bflo(q[0])  + bfhi(k0.x)*bfhi(q[0])  +
            bflo(k0.y)*bflo(q[1])  + bfhi(k0.y)*bfhi(q[1])  +
            bflo(k0.z)*bflo(q[2])  + bfhi(k0.z)*bfhi(q[2])  +
            bflo(k0.w)*bflo(q[3])  + bfhi(k0.w)*bfhi(q[3])  +
            bflo(k1.x)*bflo(q[4])  + bfhi(k1.x)*bfhi(q[4])  +
            bflo(k1.y)*bflo(q[5])  + bfhi(k1.y)*bfhi(q[5])  +
            bflo(k1.z)*bflo(q[6])  + bfhi(k1.z)*bfhi(q[6])  +
            bflo(k1.w)*bflo(q[7])  + bfhi(k1.w)*bfhi(q[7])  +
            bflo(k2.x)*bflo(q[8])  + bfhi(k2.x)*bfhi(q[8])  +
            bflo(k2.y)*bflo(q[9])  + bfhi(k2.y)*bfhi(q[9])  +
            bflo(k2.z)*bflo(q[10]) + bfhi(k2.z)*bfhi(q[10]) +
            bflo(k2.w)*bflo(q[11]) + bfhi(k2.w)*bfhi(q[11]) +
            bflo(k3.x)*bflo(q[12]) + bfhi(k3.x)*bfhi(q[12]) +
            bflo(k3.y)*bflo(q[13]) + bfhi(k3.y)*bfhi(q[13]) +
            bflo(k3.z)*bflo(q[14]) + bfhi(k3.z)*bfhi(q[14]) +
            bflo(k3.w)*bflo(q[15]) + bfhi(k3.w)*bfhi(q[15]);
        s *= a;
        float ww = __expf(s);
        lsum += ww;
        float wm1 = ww - 1.0f;
        acc[0]  += wm1 * bflo(v0.x); acc[1]  += wm1 * bfhi(v0.x);
        acc[2]  += wm1 * bflo(v0.y); acc[3]  += wm1 * bfhi(v0.y);
        acc[4]  += wm1 * bflo(v0.z); acc[5]  += wm1 * bfhi(v0.z);
        acc[6]  += wm1 * bflo(v0.w); acc[7]  += wm1 * bfhi(v0.w);
        acc[8]  += wm1 * bflo(v1.x); acc[9]  += wm1 * bfhi(v1.x);
        acc[10] += wm1 * bflo(v1.y); acc[11] += wm1 * bfhi(v1.y);
        acc[12] += wm1 * bflo(v1.z); acc[13] += wm1 * bfhi(v1.z);
        acc[14] += wm1 * bflo(v1.w); acc[15] += wm1 * bfhi(v1.w);
        acc[16] += wm1 * bflo(v2.x); acc[17] += wm1 * bfhi(v2.x);
        acc[18] += wm1 * bflo(v2.y); acc[19] += wm1 * bfhi(v2.y);
        acc[20] += wm1 * bflo(v2.z); acc[21] += wm1 * bfhi(v2.z);
        acc[22] += wm1 * bflo(v2.w); acc[23] += wm1 * bfhi(v2.w);
        acc[24] += wm1 * bflo(v3.x); acc[25] += wm1 * bfhi(v3.x);
        acc[26] += wm1 * bflo(v3.y); acc[27] += wm1 * bfhi(v3.y);
        acc[28] += wm1 * bflo(v3.z); acc[29] += wm1 * bfhi(v3.z);
        acc[30] += wm1 * bflo(v3.w); acc[31] += wm1 * bfhi(v3.w);
    }

    // scalar denominator reduce (lane-local weights -> row denom)
    #pragma unroll
    for (int o = 16; o > 0; o >>= 1) lsum += __shfl_xor(lsum, o, 32);
    if (l == 0) sRd[r] = 1.0f / (lsum + (float)(NN - nnz));

    // 32-float transpose reduce, two row-batches through 17 KB buffer
    #pragma unroll
    for (int batch = 0; batch < 2; ++batch) {
        __syncthreads();
        if ((r >> 2) == batch) {
            #pragma unroll
            for (int i = 0; i < 32; ++i) sRed[r & 3][l][i] = acc[i];
        }
        __syncthreads();
        if ((r >> 2) == batch) {
            float o = 0.f;
            #pragma unroll
            for (int src = 0; src < 32; ++src) o += sRed[r & 3][src][l];
            float res = (o + vsumh[hH * HDIM + l]) * sRd[r];
            outh[((size_t)hH * NN + n) * HDIM + l] = f2bf(res);
        }
    }
}

// ---------------------------------------------------------------------------
extern "C" void kernel_launch(void* const* d_in, const int* in_sizes, int n_in,
                              void* d_out, int out_size, void* d_ws, size_t ws_size,
                              hipStream_t stream)
{
    const float* A  = (const float*)d_in[0];
    const float* h  = (const float*)d_in[1];
    const float* Wq = (const float*)d_in[2];
    const float* Wk = (const float*)d_in[3];
    const float* Wv = (const float*)d_in[4];
    const float* Wo = (const float*)d_in[5];
    const float* g1 = (const float*)d_in[6];
    const float* b1 = (const float*)d_in[7];
    const float* g2 = (const float*)d_in[8];
    const float* b2 = (const float*)d_in[9];
    const float* W1 = (const float*)d_in[10];
    const float* W2 = (const float*)d_in[11];
    float* out = (float*)d_out;
    char* w = (char*)d_ws;

    unsigned* packed = (unsigned*)(w);           // [0,2M)  nz lists
    int*    nzcnt  = (int*)(w + 2 * MB);
    ushort* h_bf   = (ushort*)(w + 3 * MB);      // 2 MB
    ushort* wqkv   = (ushort*)(w + 5 * MB);      // 384 KB
    ushort* wo_b   = (ushort*)(w + 5 * MB + 384 * 1024);   // k-permuted Wo
    ushort* w1_b   = (ushort*)(w + 5 * MB + 512 * 1024);
    ushort* w2_b   = (ushort*)(w + 5 * MB + 768 * 1024);
    ushort* qh_bf  = (ushort*)(w + 6 * MB);      // 2 MB [8][4096][32]
    ushort* kvh    = (ushort*)(w + 8 * MB);      // 4 MB [8][4096][64] k|v
    ushort* ao_hb  = (ushort*)(w + 12 * MB);     // 2 MB [8][4096][32] head-major
    float*  y      = (float*)(w + 14 * MB);      // 4 MB
    ushort* t_bf   = (ushort*)(w + 18 * MB);     // 4 MB FFN hidden
    float*  vpart  = (float*)(w + 22 * MB);      // 64 KB [64][256]
    float*  bnps   = (float*)(w + 23 * MB);
    float*  bnpq   = (float*)(w + 23 * MB + 64 * 1024);
    float*  scale1 = (float*)(w + 24 * MB);
    float*  shift1 = scale1 + 256;
    float*  scale2 = scale1 + 512;
    float*  shift2 = scale1 + 768;
    float*  vsumh  = scale1 + 1024;

    dim3 blk(256);

    // 1: bf16 conversions (Wo k-permuted)
    convert_bf<<<768, blk, 0, stream>>>(h, Wq, Wk, Wv, Wo, W1, W2,
        h_bf, wqkv, wqkv + 65536, wqkv + 131072, wo_b, w1_b, w2_b);
    // 2: fused QKV gemm + A nz-scan
    qkv_ascan<<<4864, blk, 0, stream>>>(h_bf, wqkv, qh_bf, kvh, vpart,
                                        A, packed, nzcnt);
    // 3: vsumh (tiny, coalesced)
    vsum_final<<<1, blk, 0, stream>>>(vpart, vsumh);
    // 4: fused single-pass head-partitioned attention -> ao_hb
    attn4<<<NN, blk, 0, stream>>>(qh_bf, kvh, vsumh, packed, nzcnt, ao_hb);
    // 5: Wo projection (head-major A, permuted Wo) + residual(h) -> y + BN1 partials
    gemm_bf<<<dim3(4, 64), blk, 0, stream>>>(ao_hb, wo_b,
        nullptr, nullptr, h, nullptr, nullptr, nullptr,
        y, nullptr, bnps, bnpq, NN, DIM, DIM, 2, 0, 0, 1);
    // 6: BN1 -> scale1/shift1
    colreduce_final2<<<1, dim3(1024), 0, stream>>>(bnps, bnpq, g1, b1, scale1, shift1);
    // 7: FFN1 with BN1 applied on A-load, relu, bf16 out
    gemm_bf<<<dim3(8, 64), blk, 0, stream>>>(y, w1_b,
        scale1, shift1, nullptr, nullptr, nullptr, nullptr,
        nullptr, t_bf, nullptr, nullptr, NN, DFF, DIM, 1, 1, 1, 0);
    // 8: FFN2 + recomputed BN1 residual, in-place on y, with BN2 stat partials
    gemm_bf<<<dim3(4, 64), blk, 0, stream>>>(t_bf, w2_b,
        nullptr, nullptr, nullptr, y, scale1, shift1,
        y, nullptr, bnps, bnpq, NN, DIM, DFF, 0, 3, 0, 1);
    // 9: BN2 -> scale2/shift2
    colreduce_final2<<<1, dim3(1024), 0, stream>>>(bnps, bnpq, g2, b2, scale2, shift2);
    // 10: BN2 apply -> d_out
    bn_apply_fin<<<1024, blk, 0, stream>>>(y, scale2, shift2, out);
}

// Round 13
// 95.035 us; speedup vs baseline: 1.7263x; 1.0854x over previous
//
#include <hip/hip_runtime.h>
#include <math.h>

#define NN 4096        // nodes
#define DIM 256        // hidden
#define NHEAD 8
#define HDIM 32
#define DFF 512
#define CAP 128        // max nonzeros per row (mean ~41, max ~75 at p=.01)
#define EPS_BN 1e-5f
#define QSCALE 0.0625f // D^-0.5
#define MB (1u << 20)

typedef __attribute__((ext_vector_type(8))) short short8;
typedef __attribute__((ext_vector_type(4))) float f32x4;

__device__ inline ushort f2bf(float x) {   // RNE float->bf16
    unsigned u = __builtin_bit_cast(unsigned, x);
    unsigned r = u + 0x7FFF + ((u >> 16) & 1);
    return (ushort)(r >> 16);
}
__device__ inline float bf2f(ushort u) {
    return __builtin_bit_cast(float, (unsigned)u << 16);
}
__device__ inline float bflo(unsigned u) { return __builtin_bit_cast(float, u << 16); }
__device__ inline float bfhi(unsigned u) { return __builtin_bit_cast(float, u & 0xFFFF0000u); }

// ---------------- convert WEIGHTS fp32 -> bf16 (256 blocks) ----------------
// Wq(32) Wk(32) Wv(32) Wo-permuted(32) W1(64) W2(64).
// Wo stored with k-columns permuted to [h*32+d] so the Wo GEMM can consume
// head-major attention output directly.
__global__ __launch_bounds__(256) void convert_w(
    const float* __restrict__ Wq, const float* __restrict__ Wk,
    const float* __restrict__ Wv, const float* __restrict__ Wo,
    const float* __restrict__ W1, const float* __restrict__ W2,
    ushort* __restrict__ wqkv, ushort* __restrict__ wo_b,
    ushort* __restrict__ w1_b, ushort* __restrict__ w2_b)
{
    int b = blockIdx.x, tid = threadIdx.x;
    if (b >= 96 && b < 128) {
        // Wo permuted convert: dest[row][h*32+d] = src[row][d*8+h]
        int off = b - 96;
        int row = off * 8 + (tid >> 5), t = tid & 31;
        int hh = t >> 2, dd0 = (t & 3) * 8;
        const float* src = Wo + (size_t)row * 256 + hh;
        ushort tmp[8];
        #pragma unroll
        for (int i = 0; i < 8; ++i) tmp[i] = f2bf(src[(size_t)(dd0 + i) * 8]);
        uint4 u;
        u.x = (unsigned)tmp[0] | ((unsigned)tmp[1] << 16);
        u.y = (unsigned)tmp[2] | ((unsigned)tmp[3] << 16);
        u.z = (unsigned)tmp[4] | ((unsigned)tmp[5] << 16);
        u.w = (unsigned)tmp[6] | ((unsigned)tmp[7] << 16);
        *(uint4*)(wo_b + (size_t)row * 256 + hh * 32 + dd0) = u;
        return;
    }
    const float* s; ushort* d; int off;
    if      (b < 32)  { s = Wq; d = wqkv;          off = b; }
    else if (b < 64)  { s = Wk; d = wqkv + 65536;  off = b - 32; }
    else if (b < 96)  { s = Wv; d = wqkv + 131072; off = b - 64; }
    else if (b < 192) { s = W1; d = w1_b;          off = b - 128; }
    else              { s = W2; d = w2_b;          off = b - 192; }
    size_t base = (size_t)off * 2048 + (size_t)tid * 8;
    float4 f0 = *(const float4*)(s + base);
    float4 f1 = *(const float4*)(s + base + 4);
    uint4 u;
    u.x = (unsigned)f2bf(f0.x) | ((unsigned)f2bf(f0.y) << 16);
    u.y = (unsigned)f2bf(f0.z) | ((unsigned)f2bf(f0.w) << 16);
    u.z = (unsigned)f2bf(f1.x) | ((unsigned)f2bf(f1.y) << 16);
    u.w = (unsigned)f2bf(f1.z) | ((unsigned)f2bf(f1.w) << 16);
    *(uint4*)(d + base) = u;
}

// ---------------- fused: QKV gemm (blocks 0..767, fp32 h on-load) ----------
//                  + A nz-scan (768..4863). No fences, no atomics.
#define LDP 88
#define TSTRIDE 74
__global__ __launch_bounds__(256) void qkv_ascan(
    const float* __restrict__ hF, const ushort* __restrict__ B,
    ushort* __restrict__ qh, ushort* __restrict__ kvh,
    float* __restrict__ vpart,
    const float* __restrict__ Araw, unsigned* __restrict__ packed,
    int* __restrict__ cnt)
{
    __shared__ ushort As[64][LDP];
    __shared__ ushort Bs[64][LDP];
    __shared__ float sRedS[8][64];
    int b = blockIdx.x, tid = threadIdx.x;

    if (b >= 768) {
        // ---- A-scan branch ----
        int* scan = (int*)&As[0][0];
        int n = b - 768;
        const float* row = Araw + (size_t)n * NN;
        float4 vals[4];
        int c = 0;
        #pragma unroll
        for (int i = 0; i < 4; ++i) {
            vals[i] = *(const float4*)(row + i * 1024 + tid * 4);
            c += (vals[i].x != 0.f) + (vals[i].y != 0.f)
               + (vals[i].z != 0.f) + (vals[i].w != 0.f);
        }
        scan[tid] = c;
        __syncthreads();
        for (int off = 1; off < 256; off <<= 1) {
            int t = (tid >= off) ? scan[tid - off] : 0;
            __syncthreads();
            scan[tid] += t;
            __syncthreads();
        }
        int pos = scan[tid] - c;       // exclusive prefix
        int total = scan[255];
        #pragma unroll
        for (int i = 0; i < 4; ++i) {
            int cb = i * 1024 + tid * 4;
            float4 v = vals[i];
            if (v.x != 0.f && pos < CAP) { packed[n*CAP+pos] = ((unsigned)f2bf(v.x) << 16) | (unsigned)cb;       ++pos; }
            if (v.y != 0.f && pos < CAP) { packed[n*CAP+pos] = ((unsigned)f2bf(v.y) << 16) | (unsigned)(cb + 1); ++pos; }
            if (v.z != 0.f && pos < CAP) { packed[n*CAP+pos] = ((unsigned)f2bf(v.z) << 16) | (unsigned)(cb + 2); ++pos; }
            if (v.w != 0.f && pos < CAP) { packed[n*CAP+pos] = ((unsigned)f2bf(v.w) << 16) | (unsigned)(cb + 3); ++pos; }
        }
        if (tid == 0) cnt[n] = min(total, CAP);
        return;
    }

    // ---- QKV GEMM branch (A = fp32 h, RNE-converted on load) ----
    int lane = tid & 63, w = tid >> 6;
    int wm = (w >> 1) * 32, wn = (w & 1) * 32;
    int xcd = b & 7, pos = b >> 3;
    int by = xcd * 8 + pos / 12;
    int bx = pos % 12;
    int m0 = by * 64, n0 = bx * 64;
    int l15 = lane & 15, lk = lane >> 4;
    int srow = tid >> 3;
    int scol = (tid & 7) * 8;

    f32x4 acc[2][2] = {};
    for (int k0 = 0; k0 < DIM; k0 += 64) {
        const ushort* Bg = B + (size_t)(n0 + srow) * DIM + scol + k0;
        uint4 gb0 = *(const uint4*)Bg;
        uint4 gb1 = *(const uint4*)(Bg + (size_t)32 * DIM);
        const float* Af = hF + (size_t)(m0 + srow) * DIM + scol + k0;
        float4 a0 = *(const float4*)Af;
        float4 a1 = *(const float4*)(Af + 4);
        float4 c0 = *(const float4*)(Af + (size_t)32 * DIM);
        float4 c1 = *(const float4*)(Af + (size_t)32 * DIM + 4);
        uint4 ga0, ga1;
        ga0.x = (unsigned)f2bf(a0.x) | ((unsigned)f2bf(a0.y) << 16);
        ga0.y = (unsigned)f2bf(a0.z) | ((unsigned)f2bf(a0.w) << 16);
        ga0.z = (unsigned)f2bf(a1.x) | ((unsigned)f2bf(a1.y) << 16);
        ga0.w = (unsigned)f2bf(a1.z) | ((unsigned)f2bf(a1.w) << 16);
        ga1.x = (unsigned)f2bf(c0.x) | ((unsigned)f2bf(c0.y) << 16);
        ga1.y = (unsigned)f2bf(c0.z) | ((unsigned)f2bf(c0.w) << 16);
        ga1.z = (unsigned)f2bf(c1.x) | ((unsigned)f2bf(c1.y) << 16);
        ga1.w = (unsigned)f2bf(c1.z) | ((unsigned)f2bf(c1.w) << 16);
        __syncthreads();
        *(uint4*)&As[srow][scol]      = ga0;
        *(uint4*)&As[srow + 32][scol] = ga1;
        *(uint4*)&Bs[srow][scol]      = gb0;
        *(uint4*)&Bs[srow + 32][scol] = gb1;
        __syncthreads();
        #pragma unroll
        for (int ks = 0; ks < 2; ++ks) {
            int kc = ks * 32 + lk * 8;
            short8 a0s = *(const short8*)&As[wm      + l15][kc];
            short8 a1s = *(const short8*)&As[wm + 16 + l15][kc];
            short8 b0s = *(const short8*)&Bs[wn      + l15][kc];
            short8 b1s = *(const short8*)&Bs[wn + 16 + l15][kc];
            acc[0][0] = __builtin_amdgcn_mfma_f32_16x16x32_bf16(a0s, b0s, acc[0][0], 0, 0, 0);
            acc[0][1] = __builtin_amdgcn_mfma_f32_16x16x32_bf16(a0s, b1s, acc[0][1], 0, 0, 0);
            acc[1][0] = __builtin_amdgcn_mfma_f32_16x16x32_bf16(a1s, b0s, acc[1][0], 0, 0, 0);
            acc[1][1] = __builtin_amdgcn_mfma_f32_16x16x32_bf16(a1s, b1s, acc[1][1], 0, 0, 0);
        }
    }
    // transpose via LDS (reuse As), coalesced 16B chunk stores
    ushort* sT = &As[0][0];
    int seg = n0 >> 8, ddBase = (n0 & 255) >> 3;
    float sp[2] = {0.f, 0.f};
    __syncthreads();
    #pragma unroll
    for (int mt = 0; mt < 2; ++mt)
        #pragma unroll
        for (int nt = 0; nt < 2; ++nt) {
            int col_l = wn + nt * 16 + l15;
            #pragma unroll
            for (int i = 0; i < 4; ++i) {
                int row_l = wm + mt * 16 + lk * 4 + i;
                float v = acc[mt][nt][i];
                if (seg == 0) v *= QSCALE;
                sT[row_l * TSTRIDE + col_l] = f2bf(v);
                sp[nt] += v;
            }
        }
    __syncthreads();
    for (int c = tid; c < 512; c += 256) {
        int rl = c & 63, hh = c >> 6;
        const ushort* tp = sT + rl * TSTRIDE + hh;
        uint4 pk;
        pk.x = (unsigned)tp[0]  | ((unsigned)tp[8]  << 16);
        pk.y = (unsigned)tp[16] | ((unsigned)tp[24] << 16);
        pk.z = (unsigned)tp[32] | ((unsigned)tp[40] << 16);
        pk.w = (unsigned)tp[48] | ((unsigned)tp[56] << 16);
        int row = m0 + rl;
        if (seg == 0)
            *(uint4*)(qh + ((size_t)hh * NN + row) * HDIM + ddBase) = pk;
        else
            *(uint4*)(kvh + ((size_t)hh * NN + row) * 64 +
                      ((seg == 2) ? 32 : 0) + ddBase) = pk;
    }
    if (seg == 2) {
        int slot = ((wm >> 5) << 2) | lk;
        sRedS[slot][wn + l15]      = sp[0];
        sRedS[slot][wn + 16 + l15] = sp[1];
        __syncthreads();
        if (tid < 64) {
            float ss = 0.f;
            #pragma unroll
            for (int r = 0; r < 8; ++r) ss += sRedS[r][tid];
            vpart[(size_t)by * 256 + (n0 & 255) + tid] = ss;
        }
    }
}

// ---------------- vsum final: 64 coalesced partials -> vsumh[h][d] ---------
__global__ __launch_bounds__(256) void vsum_final(
    const float* __restrict__ vpart, float* __restrict__ vsumh)
{
    int c = threadIdx.x;
    float s = 0.f;
    #pragma unroll 8
    for (int b = 0; b < 64; ++b) s += vpart[(size_t)b * 256 + c];
    vsumh[(c & 7) * HDIM + (c >> 3)] = s;
}

// ---------------- bf16 MFMA GEMM (modes 0/1/2/3), XCD-swizzled -------------
// aMode 0: A bf16 [M,K]. aMode 1: A fp32 + on-load BN (scA/shA per col).
// aMode 2: A bf16 head-major [8][NN][32] (B k-permuted to match).
// storeMode 0: Cf fp32 (+resid). 1: Cb bf16 (relu opt).
//   3: Cf fp32, residual recomputed as yres*scR+shR (Cf may alias yres).
// bnstat: per-block col sum/sumsq partials -> bnps/bnpq [nby][256].
__global__ __launch_bounds__(256) void gemm_bf(
    const void* __restrict__ Aptr, const ushort* __restrict__ B,
    const float* __restrict__ scA, const float* __restrict__ shA,
    const float* __restrict__ resid,
    const float* yres, const float* __restrict__ scR, const float* __restrict__ shR,
    float* Cf, ushort* __restrict__ Cb,
    float* __restrict__ bnps, float* __restrict__ bnpq,
    int M, int Nn, int K, int aMode, int storeMode, int relu, int bnstat)
{
    __shared__ ushort As[64][LDP];
    __shared__ ushort Bs[64][LDP];
    __shared__ float sRedS[8][64];
    __shared__ float sRedQ[8][64];
    int tid = threadIdx.x;
    int lane = tid & 63, w = tid >> 6;
    int wm = (w >> 1) * 32, wn = (w & 1) * 32;
    int nbx = gridDim.x, nbyq = gridDim.y >> 3;
    int orig = blockIdx.y * nbx + blockIdx.x;
    int xcd = orig & 7, pos = orig >> 3;
    int by = xcd * nbyq + pos / nbx;
    int bx = pos % nbx;
    int m0 = by * 64, n0 = bx * 64;
    int l15 = lane & 15, lk = lane >> 4;
    int srow = tid >> 3;
    int scol = (tid & 7) * 8;

    f32x4 acc[2][2] = {};
    for (int k0 = 0; k0 < K; k0 += 64) {
        uint4 ga0, ga1, gb0, gb1;
        const ushort* Bg = B + (size_t)(n0 + srow) * K + scol + k0;
        gb0 = *(const uint4*)Bg;
        gb1 = *(const uint4*)(Bg + (size_t)32 * K);
        if (aMode == 0) {
            const ushort* Ag = (const ushort*)Aptr + (size_t)(m0 + srow) * K + scol + k0;
            ga0 = *(const uint4*)Ag;
            ga1 = *(const uint4*)(Ag + (size_t)32 * K);
        } else if (aMode == 2) {
            int c0 = k0 + scol;
            int hh = c0 >> 5, dd = c0 & 31;
            const ushort* Ag = (const ushort*)Aptr +
                ((size_t)hh * NN + m0 + srow) * HDIM + dd;
            ga0 = *(const uint4*)Ag;
            ga1 = *(const uint4*)(Ag + (size_t)32 * HDIM);
        } else {
            const float* Af = (const float*)Aptr + (size_t)(m0 + srow) * K + scol + k0;
            float4 sc0 = *(const float4*)(scA + k0 + scol);
            float4 sc1 = *(const float4*)(scA + k0 + scol + 4);
            float4 sh0 = *(const float4*)(shA + k0 + scol);
            float4 sh1 = *(const float4*)(shA + k0 + scol + 4);
            float4 a0 = *(const float4*)Af;
            float4 a1 = *(const float4*)(Af + 4);
            float4 b0 = *(const float4*)(Af + (size_t)32 * K);
            float4 b1 = *(const float4*)(Af + (size_t)32 * K + 4);
            ga0.x = (unsigned)f2bf(a0.x*sc0.x+sh0.x) | ((unsigned)f2bf(a0.y*sc0.y+sh0.y) << 16);
            ga0.y = (unsigned)f2bf(a0.z*sc0.z+sh0.z) | ((unsigned)f2bf(a0.w*sc0.w+sh0.w) << 16);
            ga0.z = (unsigned)f2bf(a1.x*sc1.x+sh1.x) | ((unsigned)f2bf(a1.y*sc1.y+sh1.y) << 16);
            ga0.w = (unsigned)f2bf(a1.z*sc1.z+sh1.z) | ((unsigned)f2bf(a1.w*sc1.w+sh1.w) << 16);
            ga1.x = (unsigned)f2bf(b0.x*sc0.x+sh0.x) | ((unsigned)f2bf(b0.y*sc0.y+sh0.y) << 16);
            ga1.y = (unsigned)f2bf(b0.z*sc0.z+sh0.z) | ((unsigned)f2bf(b0.w*sc0.w+sh0.w) << 16);
            ga1.z = (unsigned)f2bf(b1.x*sc1.x+sh1.x) | ((unsigned)f2bf(b1.y*sc1.y+sh1.y) << 16);
            ga1.w = (unsigned)f2bf(b1.z*sc1.z+sh1.z) | ((unsigned)f2bf(b1.w*sc1.w+sh1.w) << 16);
        }
        __syncthreads();
        *(uint4*)&As[srow][scol]      = ga0;
        *(uint4*)&As[srow + 32][scol] = ga1;
        *(uint4*)&Bs[srow][scol]      = gb0;
        *(uint4*)&Bs[srow + 32][scol] = gb1;
        __syncthreads();
        #pragma unroll
        for (int ks = 0; ks < 2; ++ks) {
            int kc = ks * 32 + lk * 8;
            short8 a0 = *(const short8*)&As[wm      + l15][kc];
            short8 a1 = *(const short8*)&As[wm + 16 + l15][kc];
            short8 b0 = *(const short8*)&Bs[wn      + l15][kc];
            short8 b1 = *(const short8*)&Bs[wn + 16 + l15][kc];
            acc[0][0] = __builtin_amdgcn_mfma_f32_16x16x32_bf16(a0, b0, acc[0][0], 0, 0, 0);
            acc[0][1] = __builtin_amdgcn_mfma_f32_16x16x32_bf16(a0, b1, acc[0][1], 0, 0, 0);
            acc[1][0] = __builtin_amdgcn_mfma_f32_16x16x32_bf16(a1, b0, acc[1][0], 0, 0, 0);
            acc[1][1] = __builtin_amdgcn_mfma_f32_16x16x32_bf16(a1, b1, acc[1][1], 0, 0, 0);
        }
    }

    float sp[2] = {0.f, 0.f}, qp[2] = {0.f, 0.f};
    #pragma unroll
    for (int mt = 0; mt < 2; ++mt) {
        #pragma unroll
        for (int nt = 0; nt < 2; ++nt) {
            int col = n0 + wn + nt * 16 + l15;
            #pragma unroll
            for (int i = 0; i < 4; ++i) {
                int row = m0 + wm + mt * 16 + lk * 4 + i;
                float v = acc[mt][nt][i];
                if (storeMode == 0) {
                    if (resid) v += resid[(size_t)row * Nn + col];
                    Cf[(size_t)row * Nn + col] = v;
                } else if (storeMode == 1) {
                    if (relu) v = fmaxf(v, 0.f);
                    Cb[(size_t)row * Nn + col] = f2bf(v);
                } else { // 3
                    v += yres[(size_t)row * Nn + col] * scR[col] + shR[col];
                    Cf[(size_t)row * Nn + col] = v;
                }
                if (bnstat) { sp[nt] += v; qp[nt] += v * v; }
            }
        }
    }
    if (bnstat) {
        int slot = ((wm >> 5) << 2) | lk;
        sRedS[slot][wn + l15]      = sp[0];
        sRedQ[slot][wn + l15]      = qp[0];
        sRedS[slot][wn + 16 + l15] = sp[1];
        sRedQ[slot][wn + 16 + l15] = qp[1];
        __syncthreads();
        if (tid < 64) {
            float ss = 0.f, qq = 0.f;
            #pragma unroll
            for (int r = 0; r < 8; ++r) { ss += sRedS[r][tid]; qq += sRedQ[r][tid]; }
            bnps[(size_t)by * DIM + n0 + tid] = ss;
            bnpq[(size_t)by * DIM + n0 + tid] = qq;
        }
    }
}

// ---------------- BN stats final: 64 partials -> scale/shift ---------------
__global__ __launch_bounds__(1024) void colreduce_final2(
    const float* __restrict__ ps, const float* __restrict__ pq,
    const float* __restrict__ g, const float* __restrict__ bsh,
    float* __restrict__ scale, float* __restrict__ shift)
{
    __shared__ float rs_[4][256], rq_[4][256];
    int t = threadIdx.x;
    int c = t & 255, qd = t >> 8;
    float s = 0.f, q = 0.f;
    for (int b = qd; b < 64; b += 4) {
        s += ps[b * DIM + c];
        q += pq[b * DIM + c];
    }
    rs_[qd][c] = s; rq_[qd][c] = q;
    __syncthreads();
    if (qd == 0) {
        s = rs_[0][c] + rs_[1][c] + rs_[2][c] + rs_[3][c];
        q = rq_[0][c] + rq_[1][c] + rq_[2][c] + rq_[3][c];
        float m = s * (1.f / NN);
        float var = q * (1.f / NN) - m * m;
        float rstd = rsqrtf(var + EPS_BN);
        float sc = rstd * g[c];
        scale[c] = sc;
        shift[c] = bsh[c] - m * sc;
    }
}

__global__ __launch_bounds__(256) void bn_apply_fin(
    const float* __restrict__ x, const float* __restrict__ scale,
    const float* __restrict__ shift, float* __restrict__ out)
{
    int tid = threadIdx.x;
    size_t i = (size_t)blockIdx.x * 1024 + (size_t)tid * 4;
    int c = (tid * 4) & 255;
    float4 v = *(const float4*)(x + i);
    float4 sc = *(const float4*)(scale + c);
    float4 sh = *(const float4*)(shift + c);
    float4 r;
    r.x = v.x * sc.x + sh.x;
    r.y = v.y * sc.y + sh.y;
    r.z = v.z * sc.z + sh.z;
    r.w = v.w * sc.w + sh.w;
    *(float4*)(out + i) = r;
}

// ---------------- head-partitioned sparse masked attention (R9 form) -------
// Block b: head hH = b&7 (-> XCD b&7), rows rg*8..rg*8+7. Per-XCD working
// set = one head's q+kv (~768 KB) -> L2-resident. No-max-shift softmax.
__global__ __launch_bounds__(256) void attn3(
    const ushort* __restrict__ qh, const ushort* __restrict__ kvh,
    const float* __restrict__ vsumh,
    const unsigned* __restrict__ packed, const int* __restrict__ cnt,
    ushort* __restrict__ outh)
{
    __shared__ float    sQ[8][32];
    __shared__ unsigned sPk[8][CAP];
    __shared__ float    sS[8][CAP];
    __shared__ float    sRd[8];

    int tid = threadIdx.x, b = blockIdx.x;
    int hH = b & 7, rg = b >> 3;
    int r = tid >> 5, l = tid & 31;
    int n = rg * 8 + r;
    int nnz = cnt[n];

    sQ[r][l] = bf2f(qh[((size_t)hH * NN + n) * HDIM + l]);
    for (int j = l; j < nnz; j += 32) sPk[r][j] = packed[n * CAP + j];
    __syncthreads();

    // phase 1: scores + weights + denom (32 lanes split j within the row)
    float4 qreg[8];
    #pragma unroll
    for (int t = 0; t < 8; ++t) qreg[t] = ((const float4*)sQ[r])[t];
    float lsum = 0.0f;
    for (int j = l; j < nnz; j += 32) {
        unsigned pk = sPk[r][j];
        int m = pk & 0xFFFF;
        float a = bfhi(pk);
        const uint4* kp = (const uint4*)(kvh + ((size_t)hH * NN + m) * 64);
        uint4 k0 = kp[0], k1 = kp[1], k2 = kp[2], k3 = kp[3];
        float s =
            bflo(k0.x)*qreg[0].x + bfhi(k0.x)*qreg[0].y +
            bflo(k0.y)*qreg[0].z + bfhi(k0.y)*qreg[0].w +
            bflo(k0.z)*qreg[1].x + bfhi(k0.z)*qreg[1].y +
            bflo(k0.w)*qreg[1].z + bfhi(k0.w)*qreg[1].w +
            bflo(k1.x)*qreg[2].x + bfhi(k1.x)*qreg[2].y +
            bflo(k1.y)*qreg[2].z + bfhi(k1.y)*qreg[2].w +
            bflo(k1.z)*qreg[3].x + bfhi(k1.z)*qreg[3].y +
            bflo(k1.w)*qreg[3].z + bfhi(k1.w)*qreg[3].w +
            bflo(k2.x)*qreg[4].x + bfhi(k2.x)*qreg[4].y +
            bflo(k2.y)*qreg[4].z + bfhi(k2.y)*qreg[4].w +
            bflo(k2.z)*qreg[5].x + bfhi(k2.z)*qreg[5].y +
            bflo(k2.w)*qreg[5].z + bfhi(k2.w)*qreg[5].w +
            bflo(k3.x)*qreg[6].x + bfhi(k3.x)*qreg[6].y +
            bflo(k3.y)*qreg[6].z + bfhi(k3.y)*qreg[6].w +
            bflo(k3.z)*qreg[7].x + bfhi(k3.z)*qreg[7].y +
            bflo(k3.w)*qreg[7].z + bfhi(k3.w)*qreg[7].w;
        s *= a;
        float ww = __expf(s);
        sS[r][j] = ww - 1.0f;
        lsum += ww;
    }
    #pragma unroll
    for (int o = 16; o > 0; o >>= 1) lsum += __shfl_xor(lsum, o, 32);
    if (l == 0) sRd[r] = 1.0f / (lsum + (float)(NN - nnz));
    __syncthreads();

    // phase 2: lane = (jsub = l>>3, dq = l&7); 4-way j split, uint2 gathers
    int jsub = l >> 3, dq = l & 7;
    const ushort* vbase = kvh + (size_t)hH * NN * 64 + 32 + dq * 4;
    float a0 = 0.f, a1 = 0.f, a2 = 0.f, a3 = 0.f;
    for (int j = jsub; j < nnz; j += 4) {
        float ww = sS[r][j];
        int m = sPk[r][j] & 0xFFFF;
        uint2 vv = *(const uint2*)(vbase + (size_t)m * 64);
        a0 += ww * bflo(vv.x); a1 += ww * bfhi(vv.x);
        a2 += ww * bflo(vv.y); a3 += ww * bfhi(vv.y);
    }
    #pragma unroll
    for (int o = 8; o < 32; o <<= 1) {
        a0 += __shfl_xor(a0, o, 32);
        a1 += __shfl_xor(a1, o, 32);
        a2 += __shfl_xor(a2, o, 32);
        a3 += __shfl_xor(a3, o, 32);
    }
    if (jsub == 0) {
        float rd = sRd[r];
        int d0 = dq * 4;
        const float* vs = vsumh + hH * HDIM + d0;
        float r0 = (a0 + vs[0]) * rd;
        float r1 = (a1 + vs[1]) * rd;
        float r2 = (a2 + vs[2]) * rd;
        float r3 = (a3 + vs[3]) * rd;
        uint2 st;
        st.x = (unsigned)f2bf(r0) | ((unsigned)f2bf(r1) << 16);
        st.y = (unsigned)f2bf(r2) | ((unsigned)f2bf(r3) << 16);
        *(uint2*)(outh + ((size_t)hH * NN + n) * HDIM + d0) = st;
    }
}

// ---------------------------------------------------------------------------
extern "C" void kernel_launch(void* const* d_in, const int* in_sizes, int n_in,
                              void* d_out, int out_size, void* d_ws, size_t ws_size,
                              hipStream_t stream)
{
    const float* A  = (const float*)d_in[0];
    const float* h  = (const float*)d_in[1];
    const float* Wq = (const float*)d_in[2];
    const float* Wk = (const float*)d_in[3];
    const float* Wv = (const float*)d_in[4];
    const float* Wo = (const float*)d_in[5];
    const float* g1 = (const float*)d_in[6];
    const float* b1 = (const float*)d_in[7];
    const float* g2 = (const float*)d_in[8];
    const float* b2 = (const float*)d_in[9];
    const float* W1 = (const float*)d_in[10];
    const float* W2 = (const float*)d_in[11];
    float* out = (float*)d_out;
    char* w = (char*)d_ws;

    unsigned* packed = (unsigned*)(w);           // [0,2M)  nz lists
    int*    nzcnt  = (int*)(w + 2 * MB);
    ushort* wqkv   = (ushort*)(w + 5 * MB);      // 384 KB
    ushort* wo_b   = (ushort*)(w + 5 * MB + 384 * 1024);   // k-permuted Wo
    ushort* w1_b   = (ushort*)(w + 5 * MB + 512 * 1024);
    ushort* w2_b   = (ushort*)(w + 5 * MB + 768 * 1024);
    ushort* qh_bf  = (ushort*)(w + 6 * MB);      // 2 MB [8][4096][32]
    ushort* kvh    = (ushort*)(w + 8 * MB);      // 4 MB [8][4096][64] k|v
    ushort* ao_hb  = (ushort*)(w + 12 * MB);     // 2 MB [8][4096][32] head-major
    float*  y      = (float*)(w + 14 * MB);      // 4 MB
    ushort* t_bf   = (ushort*)(w + 18 * MB);     // 4 MB FFN hidden
    float*  vpart  = (float*)(w + 22 * MB);      // 64 KB [64][256]
    float*  bnps   = (float*)(w + 23 * MB);
    float*  bnpq   = (float*)(w + 23 * MB + 64 * 1024);
    float*  scale1 = (float*)(w + 24 * MB);
    float*  shift1 = scale1 + 256;
    float*  scale2 = scale1 + 512;
    float*  shift2 = scale1 + 768;
    float*  vsumh  = scale1 + 1024;

    dim3 blk(256);

    // 1: weight conversions only (Wo k-permuted)
    convert_w<<<256, blk, 0, stream>>>(Wq, Wk, Wv, Wo, W1, W2,
                                       wqkv, wo_b, w1_b, w2_b);
    // 2: fused QKV gemm (fp32 h converted on-load) + A nz-scan
    qkv_ascan<<<4864, blk, 0, stream>>>(h, wqkv, qh_bf, kvh, vpart,
                                        A, packed, nzcnt);
    // 3: vsumh (tiny, coalesced)
    vsum_final<<<1, blk, 0, stream>>>(vpart, vsumh);
    // 4: head-partitioned attention -> head-major ao_hb
    attn3<<<NN, blk, 0, stream>>>(qh_bf, kvh, vsumh, packed, nzcnt, ao_hb);
    // 5: Wo projection (head-major A, permuted Wo) + residual(h) -> y + BN1 partials
    gemm_bf<<<dim3(4, 64), blk, 0, stream>>>(ao_hb, wo_b,
        nullptr, nullptr, h, nullptr, nullptr, nullptr,
        y, nullptr, bnps, bnpq, NN, DIM, DIM, 2, 0, 0, 1);
    // 6: BN1 -> scale1/shift1
    colreduce_final2<<<1, dim3(1024), 0, stream>>>(bnps, bnpq, g1, b1, scale1, shift1);
    // 7: FFN1 with BN1 applied on A-load, relu, bf16 out
    gemm_bf<<<dim3(8, 64), blk, 0, stream>>>(y, w1_b,
        scale1, shift1, nullptr, nullptr, nullptr, nullptr,
        nullptr, t_bf, nullptr, nullptr, NN, DFF, DIM, 1, 1, 1, 0);
    // 8: FFN2 + recomputed BN1 residual, in-place on y, with BN2 stat partials
    gemm_bf<<<dim3(4, 64), blk, 0, stream>>>(t_bf, w2_b,
        nullptr, nullptr, nullptr, y, scale1, shift1,
        y, nullptr, bnps, bnpq, NN, DIM, DFF, 0, 3, 0, 1);
    // 9: BN2 -> scale2/shift2
    colreduce_final2<<<1, dim3(1024), 0, stream>>>(bnps, bnpq, g2, b2, scale2, shift2);
    // 10: BN2 apply -> d_out
    bn_apply_fin<<<1024, blk, 0, stream>>>(y, scale2, shift2, out);
}

// Round 14
// 90.108 us; speedup vs baseline: 1.8207x; 1.0547x over previous
//
#include <hip/hip_runtime.h>
#include <math.h>

#define NN 4096        // nodes
#define DIM 256        // hidden
#define NHEAD 8
#define HDIM 32
#define DFF 512
#define CAP 128        // max nonzeros per row (mean ~41, max ~75 at p=.01)
#define EPS_BN 1e-5f
#define QSCALE 0.0625f // D^-0.5
#define MB (1u << 20)

typedef __attribute__((ext_vector_type(8))) short short8;
typedef __attribute__((ext_vector_type(4))) float f32x4;

__device__ inline ushort f2bf(float x) {   // RNE float->bf16
    unsigned u = __builtin_bit_cast(unsigned, x);
    unsigned r = u + 0x7FFF + ((u >> 16) & 1);
    return (ushort)(r >> 16);
}
__device__ inline float bf2f(ushort u) {
    return __builtin_bit_cast(float, (unsigned)u << 16);
}
__device__ inline float bflo(unsigned u) { return __builtin_bit_cast(float, u << 16); }
__device__ inline float bfhi(unsigned u) { return __builtin_bit_cast(float, u & 0xFFFF0000u); }

// ---------------- convert WEIGHTS fp32 -> bf16 (256 blocks) ----------------
// Wq(32) Wk(32) Wv(32) Wo-permuted(32) W1(64) W2(64).
__global__ __launch_bounds__(256) void convert_w(
    const float* __restrict__ Wq, const float* __restrict__ Wk,
    const float* __restrict__ Wv, const float* __restrict__ Wo,
    const float* __restrict__ W1, const float* __restrict__ W2,
    ushort* __restrict__ wqkv, ushort* __restrict__ wo_b,
    ushort* __restrict__ w1_b, ushort* __restrict__ w2_b)
{
    int b = blockIdx.x, tid = threadIdx.x;
    if (b >= 96 && b < 128) {
        // Wo permuted convert: dest[row][h*32+d] = src[row][d*8+h]
        int off = b - 96;
        int row = off * 8 + (tid >> 5), t = tid & 31;
        int hh = t >> 2, dd0 = (t & 3) * 8;
        const float* src = Wo + (size_t)row * 256 + hh;
        ushort tmp[8];
        #pragma unroll
        for (int i = 0; i < 8; ++i) tmp[i] = f2bf(src[(size_t)(dd0 + i) * 8]);
        uint4 u;
        u.x = (unsigned)tmp[0] | ((unsigned)tmp[1] << 16);
        u.y = (unsigned)tmp[2] | ((unsigned)tmp[3] << 16);
        u.z = (unsigned)tmp[4] | ((unsigned)tmp[5] << 16);
        u.w = (unsigned)tmp[6] | ((unsigned)tmp[7] << 16);
        *(uint4*)(wo_b + (size_t)row * 256 + hh * 32 + dd0) = u;
        return;
    }
    const float* s; ushort* d; int off;
    if      (b < 32)  { s = Wq; d = wqkv;          off = b; }
    else if (b < 64)  { s = Wk; d = wqkv + 65536;  off = b - 32; }
    else if (b < 96)  { s = Wv; d = wqkv + 131072; off = b - 64; }
    else if (b < 192) { s = W1; d = w1_b;          off = b - 128; }
    else              { s = W2; d = w2_b;          off = b - 192; }
    size_t base = (size_t)off * 2048 + (size_t)tid * 8;
    float4 f0 = *(const float4*)(s + base);
    float4 f1 = *(const float4*)(s + base + 4);
    uint4 u;
    u.x = (unsigned)f2bf(f0.x) | ((unsigned)f2bf(f0.y) << 16);
    u.y = (unsigned)f2bf(f0.z) | ((unsigned)f2bf(f0.w) << 16);
    u.z = (unsigned)f2bf(f1.x) | ((unsigned)f2bf(f1.y) << 16);
    u.w = (unsigned)f2bf(f1.z) | ((unsigned)f2bf(f1.w) << 16);
    *(uint4*)(d + base) = u;
}

// ---------------- fused: QKV gemm (blocks 0..767, fp32 h on-load) ----------
//                  + A nz-scan (768..4863). No fences, no atomics.
#define LDP 88
#define TSTRIDE 74
__global__ __launch_bounds__(256) void qkv_ascan(
    const float* __restrict__ hF, const ushort* __restrict__ B,
    ushort* __restrict__ qh, ushort* __restrict__ kvh,
    float* __restrict__ vpart,
    const float* __restrict__ Araw, unsigned* __restrict__ packed,
    int* __restrict__ cnt)
{
    __shared__ ushort As[64][LDP];
    __shared__ ushort Bs[64][LDP];
    __shared__ float sRedS[8][64];
    int b = blockIdx.x, tid = threadIdx.x;

    if (b >= 768) {
        // ---- A-scan branch ----
        int* scan = (int*)&As[0][0];
        int n = b - 768;
        const float* row = Araw + (size_t)n * NN;
        float4 vals[4];
        int c = 0;
        #pragma unroll
        for (int i = 0; i < 4; ++i) {
            vals[i] = *(const float4*)(row + i * 1024 + tid * 4);
            c += (vals[i].x != 0.f) + (vals[i].y != 0.f)
               + (vals[i].z != 0.f) + (vals[i].w != 0.f);
        }
        scan[tid] = c;
        __syncthreads();
        for (int off = 1; off < 256; off <<= 1) {
            int t = (tid >= off) ? scan[tid - off] : 0;
            __syncthreads();
            scan[tid] += t;
            __syncthreads();
        }
        int pos = scan[tid] - c;       // exclusive prefix
        int total = scan[255];
        #pragma unroll
        for (int i = 0; i < 4; ++i) {
            int cb = i * 1024 + tid * 4;
            float4 v = vals[i];
            if (v.x != 0.f && pos < CAP) { packed[n*CAP+pos] = ((unsigned)f2bf(v.x) << 16) | (unsigned)cb;       ++pos; }
            if (v.y != 0.f && pos < CAP) { packed[n*CAP+pos] = ((unsigned)f2bf(v.y) << 16) | (unsigned)(cb + 1); ++pos; }
            if (v.z != 0.f && pos < CAP) { packed[n*CAP+pos] = ((unsigned)f2bf(v.z) << 16) | (unsigned)(cb + 2); ++pos; }
            if (v.w != 0.f && pos < CAP) { packed[n*CAP+pos] = ((unsigned)f2bf(v.w) << 16) | (unsigned)(cb + 3); ++pos; }
        }
        if (tid == 0) cnt[n] = min(total, CAP);
        return;
    }

    // ---- QKV GEMM branch (A = fp32 h, RNE-converted on load) ----
    int lane = tid & 63, w = tid >> 6;
    int wm = (w >> 1) * 32, wn = (w & 1) * 32;
    int xcd = b & 7, pos = b >> 3;
    int by = xcd * 8 + pos / 12;
    int bx = pos % 12;
    int m0 = by * 64, n0 = bx * 64;
    int l15 = lane & 15, lk = lane >> 4;
    int srow = tid >> 3;
    int scol = (tid & 7) * 8;

    f32x4 acc[2][2] = {};
    for (int k0 = 0; k0 < DIM; k0 += 64) {
        const ushort* Bg = B + (size_t)(n0 + srow) * DIM + scol + k0;
        uint4 gb0 = *(const uint4*)Bg;
        uint4 gb1 = *(const uint4*)(Bg + (size_t)32 * DIM);
        const float* Af = hF + (size_t)(m0 + srow) * DIM + scol + k0;
        float4 a0 = *(const float4*)Af;
        float4 a1 = *(const float4*)(Af + 4);
        float4 c0 = *(const float4*)(Af + (size_t)32 * DIM);
        float4 c1 = *(const float4*)(Af + (size_t)32 * DIM + 4);
        uint4 ga0, ga1;
        ga0.x = (unsigned)f2bf(a0.x) | ((unsigned)f2bf(a0.y) << 16);
        ga0.y = (unsigned)f2bf(a0.z) | ((unsigned)f2bf(a0.w) << 16);
        ga0.z = (unsigned)f2bf(a1.x) | ((unsigned)f2bf(a1.y) << 16);
        ga0.w = (unsigned)f2bf(a1.z) | ((unsigned)f2bf(a1.w) << 16);
        ga1.x = (unsigned)f2bf(c0.x) | ((unsigned)f2bf(c0.y) << 16);
        ga1.y = (unsigned)f2bf(c0.z) | ((unsigned)f2bf(c0.w) << 16);
        ga1.z = (unsigned)f2bf(c1.x) | ((unsigned)f2bf(c1.y) << 16);
        ga1.w = (unsigned)f2bf(c1.z) | ((unsigned)f2bf(c1.w) << 16);
        __syncthreads();
        *(uint4*)&As[srow][scol]      = ga0;
        *(uint4*)&As[srow + 32][scol] = ga1;
        *(uint4*)&Bs[srow][scol]      = gb0;
        *(uint4*)&Bs[srow + 32][scol] = gb1;
        __syncthreads();
        #pragma unroll
        for (int ks = 0; ks < 2; ++ks) {
            int kc = ks * 32 + lk * 8;
            short8 a0s = *(const short8*)&As[wm      + l15][kc];
            short8 a1s = *(const short8*)&As[wm + 16 + l15][kc];
            short8 b0s = *(const short8*)&Bs[wn      + l15][kc];
            short8 b1s = *(const short8*)&Bs[wn + 16 + l15][kc];
            acc[0][0] = __builtin_amdgcn_mfma_f32_16x16x32_bf16(a0s, b0s, acc[0][0], 0, 0, 0);
            acc[0][1] = __builtin_amdgcn_mfma_f32_16x16x32_bf16(a0s, b1s, acc[0][1], 0, 0, 0);
            acc[1][0] = __builtin_amdgcn_mfma_f32_16x16x32_bf16(a1s, b0s, acc[1][0], 0, 0, 0);
            acc[1][1] = __builtin_amdgcn_mfma_f32_16x16x32_bf16(a1s, b1s, acc[1][1], 0, 0, 0);
        }
    }
    // transpose via LDS (reuse As), coalesced 16B chunk stores
    ushort* sT = &As[0][0];
    int seg = n0 >> 8, ddBase = (n0 & 255) >> 3;
    float sp[2] = {0.f, 0.f};
    __syncthreads();
    #pragma unroll
    for (int mt = 0; mt < 2; ++mt)
        #pragma unroll
        for (int nt = 0; nt < 2; ++nt) {
            int col_l = wn + nt * 16 + l15;
            #pragma unroll
            for (int i = 0; i < 4; ++i) {
                int row_l = wm + mt * 16 + lk * 4 + i;
                float v = acc[mt][nt][i];
                if (seg == 0) v *= QSCALE;
                sT[row_l * TSTRIDE + col_l] = f2bf(v);
                sp[nt] += v;
            }
        }
    __syncthreads();
    for (int c = tid; c < 512; c += 256) {
        int rl = c & 63, hh = c >> 6;
        const ushort* tp = sT + rl * TSTRIDE + hh;
        uint4 pk;
        pk.x = (unsigned)tp[0]  | ((unsigned)tp[8]  << 16);
        pk.y = (unsigned)tp[16] | ((unsigned)tp[24] << 16);
        pk.z = (unsigned)tp[32] | ((unsigned)tp[40] << 16);
        pk.w = (unsigned)tp[48] | ((unsigned)tp[56] << 16);
        int row = m0 + rl;
        if (seg == 0)
            *(uint4*)(qh + ((size_t)hh * NN + row) * HDIM + ddBase) = pk;
        else
            *(uint4*)(kvh + ((size_t)hh * NN + row) * 64 +
                      ((seg == 2) ? 32 : 0) + ddBase) = pk;
    }
    if (seg == 2) {
        int slot = ((wm >> 5) << 2) | lk;
        sRedS[slot][wn + l15]      = sp[0];
        sRedS[slot][wn + 16 + l15] = sp[1];
        __syncthreads();
        if (tid < 64) {
            float ss = 0.f;
            #pragma unroll
            for (int r = 0; r < 8; ++r) ss += sRedS[r][tid];
            vpart[(size_t)by * 256 + (n0 & 255) + tid] = ss;
        }
    }
}

// ---------------- vsum final: 64 coalesced partials -> vsumh[h][d] ---------
__global__ __launch_bounds__(256) void vsum_final(
    const float* __restrict__ vpart, float* __restrict__ vsumh)
{
    int c = threadIdx.x;
    float s = 0.f;
    #pragma unroll 8
    for (int b = 0; b < 64; ++b) s += vpart[(size_t)b * 256 + c];
    vsumh[(c & 7) * HDIM + (c >> 3)] = s;
}

// ---------------- bf16 MFMA GEMM (modes 0/1/2/3), XCD-swizzled -------------
// aMode 0: A bf16 [M,K]. aMode 1: A fp32 + on-load BN (scale/shift from LDS,
//   computed in prologue when bnfin=1). aMode 2: A bf16 head-major.
// storeMode 0: Cf fp32 (+resid). 1: Cb bf16 (relu opt).
//   3: Cf fp32, residual recomputed as yres*scR+shR (Cf may alias yres).
// bnstat: per-block col sum/sumsq partials -> bnps/bnpq [nby][256].
// bnfin: prologue reduces bnpsIn/bnpqIn (64x256) + gIn/bshIn -> LDS
//   scale/shift (aliased over sRedS/sRedQ; mutually exclusive with bnstat),
//   and redundantly writes scOut/shOut (identical bits from every block).
__global__ __launch_bounds__(256) void gemm_bf(
    const void* __restrict__ Aptr, const ushort* __restrict__ B,
    const float* __restrict__ resid,
    const float* yres, const float* __restrict__ scR, const float* __restrict__ shR,
    float* Cf, ushort* __restrict__ Cb,
    float* __restrict__ bnps, float* __restrict__ bnpq,
    const float* __restrict__ bnpsIn, const float* __restrict__ bnpqIn,
    const float* __restrict__ gIn, const float* __restrict__ bshIn,
    float* __restrict__ scOut, float* __restrict__ shOut,
    int M, int Nn, int K, int aMode, int storeMode, int relu, int bnstat,
    int bnfin)
{
    __shared__ ushort As[64][LDP];
    __shared__ ushort Bs[64][LDP];
    __shared__ float sRedS[8][64];
    __shared__ float sRedQ[8][64];
    float* sSc = &sRedS[0][0];   // alias (bnfin path only; bnstat==0 then)
    float* sSh = &sRedQ[0][0];
    int tid = threadIdx.x;
    int lane = tid & 63, w = tid >> 6;
    int wm = (w >> 1) * 32, wn = (w & 1) * 32;
    int nbx = gridDim.x, nbyq = gridDim.y >> 3;
    int orig = blockIdx.y * nbx + blockIdx.x;
    int xcd = orig & 7, pos = orig >> 3;
    int by = xcd * nbyq + pos / nbx;
    int bx = pos % nbx;
    int m0 = by * 64, n0 = bx * 64;
    int l15 = lane & 15, lk = lane >> 4;
    int srow = tid >> 3;
    int scol = (tid & 7) * 8;

    if (bnfin) {
        float s = 0.f, q = 0.f;
        #pragma unroll 8
        for (int bb = 0; bb < 64; ++bb) {
            s += bnpsIn[bb * DIM + tid];
            q += bnpqIn[bb * DIM + tid];
        }
        float m = s * (1.f / NN);
        float var = q * (1.f / NN) - m * m;
        float sc = rsqrtf(var + EPS_BN) * gIn[tid];
        float sh = bshIn[tid] - m * sc;
        sSc[tid] = sc;
        sSh[tid] = sh;
        scOut[tid] = sc;     // redundant identical writes (deterministic)
        shOut[tid] = sh;
        __syncthreads();
    }

    f32x4 acc[2][2] = {};
    for (int k0 = 0; k0 < K; k0 += 64) {
        uint4 ga0, ga1, gb0, gb1;
        const ushort* Bg = B + (size_t)(n0 + srow) * K + scol + k0;
        gb0 = *(const uint4*)Bg;
        gb1 = *(const uint4*)(Bg + (size_t)32 * K);
        if (aMode == 0) {
            const ushort* Ag = (const ushort*)Aptr + (size_t)(m0 + srow) * K + scol + k0;
            ga0 = *(const uint4*)Ag;
            ga1 = *(const uint4*)(Ag + (size_t)32 * K);
        } else if (aMode == 2) {
            int c0 = k0 + scol;
            int hh = c0 >> 5, dd = c0 & 31;
            const ushort* Ag = (const ushort*)Aptr +
                ((size_t)hh * NN + m0 + srow) * HDIM + dd;
            ga0 = *(const uint4*)Ag;
            ga1 = *(const uint4*)(Ag + (size_t)32 * HDIM);
        } else {
            const float* Af = (const float*)Aptr + (size_t)(m0 + srow) * K + scol + k0;
            float4 sc0 = *(const float4*)&sSc[k0 + scol];
            float4 sc1 = *(const float4*)&sSc[k0 + scol + 4];
            float4 sh0 = *(const float4*)&sSh[k0 + scol];
            float4 sh1 = *(const float4*)&sSh[k0 + scol + 4];
            float4 a0 = *(const float4*)Af;
            float4 a1 = *(const float4*)(Af + 4);
            float4 b0 = *(const float4*)(Af + (size_t)32 * K);
            float4 b1 = *(const float4*)(Af + (size_t)32 * K + 4);
            ga0.x = (unsigned)f2bf(a0.x*sc0.x+sh0.x) | ((unsigned)f2bf(a0.y*sc0.y+sh0.y) << 16);
            ga0.y = (unsigned)f2bf(a0.z*sc0.z+sh0.z) | ((unsigned)f2bf(a0.w*sc0.w+sh0.w) << 16);
            ga0.z = (unsigned)f2bf(a1.x*sc1.x+sh1.x) | ((unsigned)f2bf(a1.y*sc1.y+sh1.y) << 16);
            ga0.w = (unsigned)f2bf(a1.z*sc1.z+sh1.z) | ((unsigned)f2bf(a1.w*sc1.w+sh1.w) << 16);
            ga1.x = (unsigned)f2bf(b0.x*sc0.x+sh0.x) | ((unsigned)f2bf(b0.y*sc0.y+sh0.y) << 16);
            ga1.y = (unsigned)f2bf(b0.z*sc0.z+sh0.z) | ((unsigned)f2bf(b0.w*sc0.w+sh0.w) << 16);
            ga1.z = (unsigned)f2bf(b1.x*sc1.x+sh1.x) | ((unsigned)f2bf(b1.y*sc1.y+sh1.y) << 16);
            ga1.w = (unsigned)f2bf(b1.z*sc1.z+sh1.z) | ((unsigned)f2bf(b1.w*sc1.w+sh1.w) << 16);
        }
        __syncthreads();
        *(uint4*)&As[srow][scol]      = ga0;
        *(uint4*)&As[srow + 32][scol] = ga1;
        *(uint4*)&Bs[srow][scol]      = gb0;
        *(uint4*)&Bs[srow + 32][scol] = gb1;
        __syncthreads();
        #pragma unroll
        for (int ks = 0; ks < 2; ++ks) {
            int kc = ks * 32 + lk * 8;
            short8 a0 = *(const short8*)&As[wm      + l15][kc];
            short8 a1 = *(const short8*)&As[wm + 16 + l15][kc];
            short8 b0 = *(const short8*)&Bs[wn      + l15][kc];
            short8 b1 = *(const short8*)&Bs[wn + 16 + l15][kc];
            acc[0][0] = __builtin_amdgcn_mfma_f32_16x16x32_bf16(a0, b0, acc[0][0], 0, 0, 0);
            acc[0][1] = __builtin_amdgcn_mfma_f32_16x16x32_bf16(a0, b1, acc[0][1], 0, 0, 0);
            acc[1][0] = __builtin_amdgcn_mfma_f32_16x16x32_bf16(a1, b0, acc[1][0], 0, 0, 0);
            acc[1][1] = __builtin_amdgcn_mfma_f32_16x16x32_bf16(a1, b1, acc[1][1], 0, 0, 0);
        }
    }

    float sp[2] = {0.f, 0.f}, qp[2] = {0.f, 0.f};
    #pragma unroll
    for (int mt = 0; mt < 2; ++mt) {
        #pragma unroll
        for (int nt = 0; nt < 2; ++nt) {
            int col = n0 + wn + nt * 16 + l15;
            #pragma unroll
            for (int i = 0; i < 4; ++i) {
                int row = m0 + wm + mt * 16 + lk * 4 + i;
                float v = acc[mt][nt][i];
                if (storeMode == 0) {
                    if (resid) v += resid[(size_t)row * Nn + col];
                    Cf[(size_t)row * Nn + col] = v;
                } else if (storeMode == 1) {
                    if (relu) v = fmaxf(v, 0.f);
                    Cb[(size_t)row * Nn + col] = f2bf(v);
                } else { // 3
                    v += yres[(size_t)row * Nn + col] * scR[col] + shR[col];
                    Cf[(size_t)row * Nn + col] = v;
                }
                if (bnstat) { sp[nt] += v; qp[nt] += v * v; }
            }
        }
    }
    if (bnstat) {
        int slot = ((wm >> 5) << 2) | lk;
        __syncthreads();
        sRedS[slot][wn + l15]      = sp[0];
        sRedQ[slot][wn + l15]      = qp[0];
        sRedS[slot][wn + 16 + l15] = sp[1];
        sRedQ[slot][wn + 16 + l15] = qp[1];
        __syncthreads();
        if (tid < 64) {
            float ss = 0.f, qq = 0.f;
            #pragma unroll
            for (int r = 0; r < 8; ++r) { ss += sRedS[r][tid]; qq += sRedQ[r][tid]; }
            bnps[(size_t)by * DIM + n0 + tid] = ss;
            bnpq[(size_t)by * DIM + n0 + tid] = qq;
        }
    }
}

// ---------------- BN2 finalize + apply (per-block redundant finalize) ------
// 512 blocks x 8 rows. Prologue: scale2/shift2 from bnps/bnpq (written by
// FFN2) + g2/b2, all in-block (stream-ordered reads, no fences).
__global__ __launch_bounds__(256) void bn2_fin(
    const float* __restrict__ y,
    const float* __restrict__ bnps, const float* __restrict__ bnpq,
    const float* __restrict__ g, const float* __restrict__ bsh,
    float* __restrict__ out)
{
    __shared__ float sSc[256], sSh[256];
    int tid = threadIdx.x, b = blockIdx.x;
    {
        float s = 0.f, q = 0.f;
        #pragma unroll 8
        for (int bb = 0; bb < 64; ++bb) {
            s += bnps[bb * DIM + tid];
            q += bnpq[bb * DIM + tid];
        }
        float m = s * (1.f / NN);
        float var = q * (1.f / NN) - m * m;
        float sc = rsqrtf(var + EPS_BN) * g[tid];
        sSc[tid] = sc;
        sSh[tid] = bsh[tid] - m * sc;
    }
    __syncthreads();
    int c4 = (tid & 63) * 4;
    float4 sc = *(float4*)&sSc[c4];
    float4 sh = *(float4*)&sSh[c4];
    #pragma unroll
    for (int it = 0; it < 2; ++it) {
        size_t i4 = (size_t)b * 512 + it * 256 + tid;   // float4 index
        float4 v = ((const float4*)y)[i4];
        float4 r;
        r.x = v.x * sc.x + sh.x;
        r.y = v.y * sc.y + sh.y;
        r.z = v.z * sc.z + sh.z;
        r.w = v.w * sc.w + sh.w;
        ((float4*)out)[i4] = r;
    }
}

// ---------------- head-partitioned sparse masked attention (R9 form) -------
__global__ __launch_bounds__(256) void attn3(
    const ushort* __restrict__ qh, const ushort* __restrict__ kvh,
    const float* __restrict__ vsumh,
    const unsigned* __restrict__ packed, const int* __restrict__ cnt,
    ushort* __restrict__ outh)
{
    __shared__ float    sQ[8][32];
    __shared__ unsigned sPk[8][CAP];
    __shared__ float    sS[8][CAP];
    __shared__ float    sRd[8];

    int tid = threadIdx.x, b = blockIdx.x;
    int hH = b & 7, rg = b >> 3;
    int r = tid >> 5, l = tid & 31;
    int n = rg * 8 + r;
    int nnz = cnt[n];

    sQ[r][l] = bf2f(qh[((size_t)hH * NN + n) * HDIM + l]);
    for (int j = l; j < nnz; j += 32) sPk[r][j] = packed[n * CAP + j];
    __syncthreads();

    // phase 1: scores + weights + denom (32 lanes split j within the row)
    float4 qreg[8];
    #pragma unroll
    for (int t = 0; t < 8; ++t) qreg[t] = ((const float4*)sQ[r])[t];
    float lsum = 0.0f;
    for (int j = l; j < nnz; j += 32) {
        unsigned pk = sPk[r][j];
        int m = pk & 0xFFFF;
        float a = bfhi(pk);
        const uint4* kp = (const uint4*)(kvh + ((size_t)hH * NN + m) * 64);
        uint4 k0 = kp[0], k1 = kp[1], k2 = kp[2], k3 = kp[3];
        float s =
            bflo(k0.x)*qreg[0].x + bfhi(k0.x)*qreg[0].y +
            bflo(k0.y)*qreg[0].z + bfhi(k0.y)*qreg[0].w +
            bflo(k0.z)*qreg[1].x + bfhi(k0.z)*qreg[1].y +
            bflo(k0.w)*qreg[1].z + bfhi(k0.w)*qreg[1].w +
            bflo(k1.x)*qreg[2].x + bfhi(k1.x)*qreg[2].y +
            bflo(k1.y)*qreg[2].z + bfhi(k1.y)*qreg[2].w +
            bflo(k1.z)*qreg[3].x + bfhi(k1.z)*qreg[3].y +
            bflo(k1.w)*qreg[3].z + bfhi(k1.w)*qreg[3].w +
            bflo(k2.x)*qreg[4].x + bfhi(k2.x)*qreg[4].y +
            bflo(k2.y)*qreg[4].z + bfhi(k2.y)*qreg[4].w +
            bflo(k2.z)*qreg[5].x + bfhi(k2.z)*qreg[5].y +
            bflo(k2.w)*qreg[5].z + bfhi(k2.w)*qreg[5].w +
            bflo(k3.x)*qreg[6].x + bfhi(k3.x)*qreg[6].y +
            bflo(k3.y)*qreg[6].z + bfhi(k3.y)*qreg[6].w +
            bflo(k3.z)*qreg[7].x + bfhi(k3.z)*qreg[7].y +
            bflo(k3.w)*qreg[7].z + bfhi(k3.w)*qreg[7].w;
        s *= a;
        float ww = __expf(s);
        sS[r][j] = ww - 1.0f;
        lsum += ww;
    }
    #pragma unroll
    for (int o = 16; o > 0; o >>= 1) lsum += __shfl_xor(lsum, o, 32);
    if (l == 0) sRd[r] = 1.0f / (lsum + (float)(NN - nnz));
    __syncthreads();

    // phase 2: lane = (jsub = l>>3, dq = l&7); 4-way j split, uint2 gathers
    int jsub = l >> 3, dq = l & 7;
    const ushort* vbase = kvh + (size_t)hH * NN * 64 + 32 + dq * 4;
    float a0 = 0.f, a1 = 0.f, a2 = 0.f, a3 = 0.f;
    for (int j = jsub; j < nnz; j += 4) {
        float ww = sS[r][j];
        int m = sPk[r][j] & 0xFFFF;
        uint2 vv = *(const uint2*)(vbase + (size_t)m * 64);
        a0 += ww * bflo(vv.x); a1 += ww * bfhi(vv.x);
        a2 += ww * bflo(vv.y); a3 += ww * bfhi(vv.y);
    }
    #pragma unroll
    for (int o = 8; o < 32; o <<= 1) {
        a0 += __shfl_xor(a0, o, 32);
        a1 += __shfl_xor(a1, o, 32);
        a2 += __shfl_xor(a2, o, 32);
        a3 += __shfl_xor(a3, o, 32);
    }
    if (jsub == 0) {
        float rd = sRd[r];
        int d0 = dq * 4;
        const float* vs = vsumh + hH * HDIM + d0;
        float r0 = (a0 + vs[0]) * rd;
        float r1 = (a1 + vs[1]) * rd;
        float r2 = (a2 + vs[2]) * rd;
        float r3 = (a3 + vs[3]) * rd;
        uint2 st;
        st.x = (unsigned)f2bf(r0) | ((unsigned)f2bf(r1) << 16);
        st.y = (unsigned)f2bf(r2) | ((unsigned)f2bf(r3) << 16);
        *(uint2*)(outh + ((size_t)hH * NN + n) * HDIM + d0) = st;
    }
}

// ---------------------------------------------------------------------------
extern "C" void kernel_launch(void* const* d_in, const int* in_sizes, int n_in,
                              void* d_out, int out_size, void* d_ws, size_t ws_size,
                              hipStream_t stream)
{
    const float* A  = (const float*)d_in[0];
    const float* h  = (const float*)d_in[1];
    const float* Wq = (const float*)d_in[2];
    const float* Wk = (const float*)d_in[3];
    const float* Wv = (const float*)d_in[4];
    const float* Wo = (const float*)d_in[5];
    const float* g1 = (const float*)d_in[6];
    const float* b1 = (const float*)d_in[7];
    const float* g2 = (const float*)d_in[8];
    const float* b2 = (const float*)d_in[9];
    const float* W1 = (const float*)d_in[10];
    const float* W2 = (const float*)d_in[11];
    float* out = (float*)d_out;
    char* w = (char*)d_ws;

    unsigned* packed = (unsigned*)(w);           // [0,2M)  nz lists
    int*    nzcnt  = (int*)(w + 2 * MB);
    ushort* wqkv   = (ushort*)(w + 5 * MB);      // 384 KB
    ushort* wo_b   = (ushort*)(w + 5 * MB + 384 * 1024);   // k-permuted Wo
    ushort* w1_b   = (ushort*)(w + 5 * MB + 512 * 1024);
    ushort* w2_b   = (ushort*)(w + 5 * MB + 768 * 1024);
    ushort* qh_bf  = (ushort*)(w + 6 * MB);      // 2 MB [8][4096][32]
    ushort* kvh    = (ushort*)(w + 8 * MB);      // 4 MB [8][4096][64] k|v
    ushort* ao_hb  = (ushort*)(w + 12 * MB);     // 2 MB [8][4096][32] head-major
    float*  y      = (float*)(w + 14 * MB);      // 4 MB
    ushort* t_bf   = (ushort*)(w + 18 * MB);     // 4 MB FFN hidden
    float*  vpart  = (float*)(w + 22 * MB);      // 64 KB [64][256]
    float*  bnps   = (float*)(w + 23 * MB);
    float*  bnpq   = (float*)(w + 23 * MB + 64 * 1024);
    float*  scale1 = (float*)(w + 24 * MB);
    float*  shift1 = scale1 + 256;
    float*  vsumh  = scale1 + 1024;

    dim3 blk(256);

    // 1: weight conversions (Wo k-permuted)
    convert_w<<<256, blk, 0, stream>>>(Wq, Wk, Wv, Wo, W1, W2,
                                       wqkv, wo_b, w1_b, w2_b);
    // 2: fused QKV gemm (fp32 h converted on-load) + A nz-scan
    qkv_ascan<<<4864, blk, 0, stream>>>(h, wqkv, qh_bf, kvh, vpart,
                                        A, packed, nzcnt);
    // 3: vsumh (tiny, coalesced)
    vsum_final<<<1, blk, 0, stream>>>(vpart, vsumh);
    // 4: head-partitioned attention -> head-major ao_hb
    attn3<<<NN, blk, 0, stream>>>(qh_bf, kvh, vsumh, packed, nzcnt, ao_hb);
    // 5: Wo projection + residual(h) -> y, with BN1 stat partials
    gemm_bf<<<dim3(4, 64), blk, 0, stream>>>(ao_hb, wo_b,
        h, nullptr, nullptr, nullptr,
        y, nullptr, bnps, bnpq,
        nullptr, nullptr, nullptr, nullptr, nullptr, nullptr,
        NN, DIM, DIM, 2, 0, 0, 1, 0);
    // 6: FFN1 — per-block BN1 finalize (from bnps/bnpq) + on-load BN + relu
    gemm_bf<<<dim3(8, 64), blk, 0, stream>>>(y, w1_b,
        nullptr, nullptr, nullptr, nullptr,
        nullptr, t_bf, nullptr, nullptr,
        bnps, bnpq, g1, b1, scale1, shift1,
        NN, DFF, DIM, 1, 1, 1, 0, 1);
    // 7: FFN2 + recomputed BN1 residual (scale1/shift1 from FFN1), BN2 partials
    gemm_bf<<<dim3(4, 64), blk, 0, stream>>>(t_bf, w2_b,
        nullptr, y, scale1, shift1,
        y, nullptr, bnps, bnpq,
        nullptr, nullptr, nullptr, nullptr, nullptr, nullptr,
        NN, DIM, DFF, 0, 3, 0, 1, 0);
    // 8: BN2 finalize (per-block) + apply -> d_out
    bn2_fin<<<512, blk, 0, stream>>>(y, bnps, bnpq, g2, b2, out);
}